// Round 1
// 750.308 us; speedup vs baseline: 1.0302x; 1.0302x over previous
//
#include <hip/hip_runtime.h>
#include <math.h>

// Problem constants: B=8, C=512, H=W=32, N=1024, G=256, R=9
using half8 = __attribute__((ext_vector_type(8))) _Float16;
using f32x4 = __attribute__((ext_vector_type(4))) float;

// Workspace layout (f32 slots)
static constexpr size_t OFF_WGCH  = 0;           // 3*4608*512 halfs
static constexpr size_t OFF_WGCL  = 3538944;
static constexpr size_t OFF_COEF  = 7077888;     // (unused f32 slot kept for layout stability)
static constexpr size_t OFF_COEFH = 11796480;    // 4718592 halfs
static constexpr size_t OFF_COEFL = 14155776;
static constexpr size_t OFF_X     = 16515072;    // 1048576 f32
static constexpr size_t OFF_CNT   = 17563648;    // 2048 f32
static constexpr size_t OFF_CNTI  = 17565696;    // 2048 int
static constexpr size_t OFF_LISTS = 17567744;    // 98304 int
static constexpr size_t OFF_CSRO  = 17666048;    // 2049 int (pad to 2304)
static constexpr size_t OFF_CSRV  = 17668352;    // 8192 u16
static constexpr size_t OFF_BNA   = 17672448;    // 256
static constexpr size_t OFF_BNB   = 17672704;    // 256
static constexpr size_t OFF_W1H   = 17672960;    // 3*512*512 halfs
static constexpr size_t OFF_W1L   = 18066176;
static constexpr size_t OFF_W2H   = 18459392;
static constexpr size_t OFF_W2L   = 18852608;
static constexpr size_t OFF_CWH   = 19245824;    // 512*1024 halfs
static constexpr size_t OFF_CWL   = 19507968;
static constexpr size_t OFF_XH    = 19770112;    // 2048*512 halfs
static constexpr size_t OFF_XL    = 20294400;
static constexpr size_t OFF_HH    = 20818688;
static constexpr size_t OFF_HL    = 21342976;
static constexpr size_t OFF_BIG   = 21867264;    // 18874368 f32 region
static constexpr size_t OFF_GA    = 40741632;    // 4718592 f32; h1/h2 alias after coef
static constexpr size_t OFF_H1    = OFF_GA;
static constexpr size_t OFF_H2    = OFF_GA + 1048576;

__device__ inline void split_hl(float v, _Float16& hi, _Float16& lo) {
  hi = (_Float16)v;
  lo = (_Float16)(v - (float)hi);
}

// Direct global->LDS DMA, 16 B per lane. LDS dest = wave-uniform base + lane*16.
// (CK-style inttoptr casts to the builtin's addrspace-qualified params.)
__device__ inline void gll16(const void* g, void* l) {
  __builtin_amdgcn_global_load_lds(
      (__attribute__((address_space(1))) void*)(size_t)g,
      (__attribute__((address_space(3))) void*)(size_t)l, 16, 0, 0);
}

// ---------------------------------------------------------------------------
// wgc[i][j][c] = sum_r wg[i][j][r*512+c] -> fp16 hi/lo
__global__ __launch_bounds__(256) void k_collapse_wg(const float* __restrict__ wg,
                                                     _Float16* __restrict__ whi,
                                                     _Float16* __restrict__ wlo) {
  size_t idx = (size_t)blockIdx.x * 256 + threadIdx.x;   // 3*4608*512
  size_t i = idx / (4608u * 512u);
  size_t rem = idx % (4608u * 512u);
  size_t j = rem / 512u, c = rem % 512u;
  const float* p = wg + i * 4608ull * 4608ull + j * 4608ull + c;
  float s = 0.f;
#pragma unroll
  for (int r = 0; r < 9; ++r) s += p[r * 512];
  _Float16 hi, lo; split_hl(s, hi, lo);
  whi[idx] = hi; wlo[idx] = lo;
}

__global__ __launch_bounds__(256) void k_split_pair(const float* __restrict__ src,
                                                    _Float16* __restrict__ hi,
                                                    _Float16* __restrict__ lo) {
  size_t idx = (size_t)blockIdx.x * 256 + threadIdx.x;
  _Float16 h, l; split_hl(src[idx], h, l);
  hi[idx] = h; lo[idx] = l;
}

// ---------------------------------------------------------------------------
__global__ __launch_bounds__(256) void k_lists(const int* __restrict__ gl,
                                               int* __restrict__ cntI,
                                               int* __restrict__ lists) {
  int idx = blockIdx.x * 256 + threadIdx.x;  // 8192
  int b = idx >> 10, n = idx & 1023;
  int h = gl[idx];
  int pos = atomicAdd(&cntI[b * 256 + h], 1);
  if (pos < 48) lists[(b * 256 + h) * 48 + pos] = n;
}

__global__ __launch_bounds__(256) void k_cntf(const int* __restrict__ cntI,
                                              float* __restrict__ cnt) {
  int i = blockIdx.x * 256 + threadIdx.x;  // 2048
  cnt[i] = (float)cntI[i];
}

// Build CSR: csr_off[2049] (int), csr_val (u16 n-indices grouped by bg)
__global__ __launch_bounds__(256) void k_csr(const int* __restrict__ cntI,
                                             const int* __restrict__ lists,
                                             int* __restrict__ csr_off,
                                             unsigned short* __restrict__ csr_val) {
  __shared__ int wsum[256];
  __shared__ int tot[257];
  int t = threadIdx.x;
  int base = t * 8;
  int loc[8]; int s = 0;
#pragma unroll
  for (int i = 0; i < 8; ++i) {
    int c = cntI[base + i]; if (c > 48) c = 48;
    loc[i] = s; s += c;
  }
  wsum[t] = s;
  __syncthreads();
  if (t == 0) {
    int a = 0;
    for (int i = 0; i < 256; ++i) { tot[i] = a; a += wsum[i]; }
    tot[256] = a;
  }
  __syncthreads();
  int off0 = tot[t];
#pragma unroll
  for (int i = 0; i < 8; ++i) {
    int bg = base + i;
    int o = off0 + loc[i];
    csr_off[bg] = o;
    int c = cntI[bg]; if (c > 48) c = 48;
    for (int j = 0; j < c; ++j)
      csr_val[o + j] = (unsigned short)(lists[bg * 48 + j] & 1023);
  }
  if (t == 0) csr_off[2048] = tot[256];
}

// ---------------------------------------------------------------------------
// t2[(r*1024+n)*2048 + bg] = sum_{m in members(bg)} adj[r,n,m]
__global__ __launch_bounds__(256) void k_t2_gather(const float* __restrict__ adj,
                                                   const int* __restrict__ csr_off,
                                                   const unsigned short* __restrict__ csr_val,
                                                   float* __restrict__ t2) {
  __shared__ float rows[8][1032];           // 33 KB -> 4 blocks/CU
  int t = threadIdx.x;
  int r = blockIdx.y;
  int n0 = blockIdx.x * 8;
  const float4* src = (const float4*)(adj + ((size_t)r * 1024 + n0) * 1024);
  for (int k = t; k < 2048; k += 256) {
    float4 v = src[k];
    int n = k >> 8;
    int m = (k & 255) << 2;
    *(float4*)&rows[n][m] = v;   // (n*1032+m)*4 bytes, 16B-aligned
  }
  __syncthreads();
#pragma unroll
  for (int j = 0; j < 8; ++j) {
    int bg = j * 256 + t;
    int o0 = csr_off[bg], o1 = csr_off[bg + 1];
    float s[8] = {0.f, 0.f, 0.f, 0.f, 0.f, 0.f, 0.f, 0.f};
    for (int i = o0; i < o1; ++i) {
      int m = csr_val[i];
#pragma unroll
      for (int n = 0; n < 8; ++n) s[n] += rows[n][m];   // 8 independent reads
    }
    size_t base = ((size_t)r * 1024 + n0) * 2048 + bg;
#pragma unroll
    for (int n = 0; n < 8; ++n) t2[base + (size_t)n * 2048] = s[n];
  }
}

// ---------------------------------------------------------------------------
// ga[b,r,g,h] = sum_{n in members(b,h)} t2[(r*1024+n)*2048 + b*256+g]
__global__ __launch_bounds__(256) void k_ga_gather(const float* __restrict__ t2,
                                                   const int* __restrict__ cntI,
                                                   const int* __restrict__ lists,
                                                   float* __restrict__ ga) {
  __shared__ float tile[256 * 17];
  int t = threadIdx.x;            // g
  int h16 = blockIdx.x & 15;
  int r = (blockIdx.x >> 4) % 9;
  int b = (blockIdx.x >> 4) / 9;
  const float* t2b = t2 + (size_t)r * 1024 * 2048 + b * 256 + t;
  for (int hh = 0; hh < 16; ++hh) {
    int h = h16 * 16 + hh;
    int cnt = cntI[b * 256 + h]; if (cnt > 48) cnt = 48;
    const int* lst = lists + (b * 256 + h) * 48;
    float acc = 0.f;
    for (int i = 0; i < cnt; ++i) acc += t2b[(size_t)lst[i] * 2048];
    tile[t * 17 + hh] = acc;
  }
  __syncthreads();
  size_t base = ((size_t)(b * 9 + r) * 256) * 256 + h16 * 16;
  for (int j = 0; j < 16; ++j) {
    int flat = j * 256 + t;
    int g = flat >> 4, hh = flat & 15;
    ga[base + (size_t)g * 256 + hh] = tile[g * 17 + hh];
  }
}

// ---------------------------------------------------------------------------
// coef[b,r,g,h] = num / (sum_h ga[b,r,g,h] + 1); writes fp16 hi/lo directly.
__global__ __launch_bounds__(256) void k_coef(const float* __restrict__ ga,
                                              _Float16* __restrict__ chi,
                                              _Float16* __restrict__ clo) {
  __shared__ float red[256];
  int tid = threadIdx.x;
  int g = blockIdx.x & 255;
  int r = (blockIdx.x >> 8) % 9;
  int b = (blockIdx.x >> 8) / 9;
  size_t base = (((size_t)b * 9 + r) * 256 + g) * 256;
  float v = ga[base + tid];
  red[tid] = v;
  __syncthreads();
  for (int off = 128; off; off >>= 1) {
    if (tid < off) red[tid] += red[tid + off];
    __syncthreads();
  }
  float denom = red[0] + 1.0f;
  float num;
  if (r == 3) {
    num = v;
  } else {
    float vf = ga[((((size_t)(7 - b)) * 9 + r) * 256 + g) * 256 + tid];
    num = fmaxf(v - vf, 0.f);
  }
  float c = num / denom;
  _Float16 hi, lo; split_hl(c, hi, lo);
  chi[base + tid] = hi; clo[base + tid] = lo;
}

// ---------------------------------------------------------------------------
// Pool via CSR gather; also emits x hi/lo halves (fused split).
__global__ __launch_bounds__(256) void k_pool_csr(const float* __restrict__ inp,
                                                  const int* __restrict__ csr_off,
                                                  const unsigned short* __restrict__ csr_val,
                                                  float* __restrict__ x,
                                                  _Float16* __restrict__ xh,
                                                  _Float16* __restrict__ xl) {
  __shared__ float rows[8][1032];         // 33 KB
  __shared__ int offs[257];
  __shared__ unsigned short vals[1024];
  int t = threadIdx.x;
  int b = blockIdx.x >> 6, cch = blockIdx.x & 63;
  const float4* src = (const float4*)(inp + (size_t)b * 524288 + (size_t)cch * 8 * 1024);
  for (int k = t; k < 2048; k += 256) {
    float4 v = src[k];
    int c = k >> 8;
    int m = (k & 255) << 2;
    *(float4*)&rows[c][m] = v;
  }
  for (int k = t; k < 257; k += 256) offs[k] = csr_off[b * 256 + k];
  __syncthreads();
  int vbase = offs[0];
  int nv = offs[256] - vbase;
  for (int k = t; k < nv; k += 256) vals[k] = csr_val[vbase + k];
  __syncthreads();
  int g = t;
  int o0 = offs[g] - vbase, o1 = offs[g + 1] - vbase;
  float s[8] = {0.f, 0.f, 0.f, 0.f, 0.f, 0.f, 0.f, 0.f};
  for (int i = o0; i < o1; ++i) {
    int n = vals[i];
#pragma unroll
    for (int c = 0; c < 8; ++c) s[c] += rows[c][n];
  }
  const float sc = 1.0f / (1.0f + 1e-7f);
  size_t xbase = ((size_t)b * 256 + g) * 512 + cch * 8;
#pragma unroll
  for (int c = 0; c < 8; ++c) {
    float v = s[c] * sc;
    x[xbase + c] = v;
    _Float16 hi, lo; split_hl(v, hi, lo);
    xh[xbase + c] = hi; xl[xbase + c] = lo;
  }
}

// ---------------------------------------------------------------------------
// Fused hi/lo NT MFMA, 128(M) x 64(N) tile, 4 waves 2x2 (wave: 64x32).
// global_load_lds staging into linear [rows][32]-half LDS (m97 pattern):
// chunk = 16 rows x 64 B = 1 KB per wave-instruction; fragment ds_read_b128
// is a contiguous 1 KB cover -> conflict-free; no ds_writes at all.
__global__ __launch_bounds__(256) void k_mfma_nt3f(const _Float16* __restrict__ Ahi,
                                                   const _Float16* __restrict__ Alo,
                                                   const _Float16* __restrict__ Bhi,
                                                   const _Float16* __restrict__ Blo,
                                                   float* __restrict__ C,
                                                   const float* __restrict__ bias,
                                                   int M, int N, int K,
                                                   size_t Bbs, size_t Cbs) {
  __shared__ __align__(16) _Float16 Ash[128][32];
  __shared__ __align__(16) _Float16 Asl[128][32];
  __shared__ __align__(16) _Float16 Bsh[64][32];
  __shared__ __align__(16) _Float16 Bsl[64][32];
  int tid = threadIdx.x;
  int z = blockIdx.z;
  const _Float16* Bh = Bhi + (size_t)z * Bbs;
  const _Float16* Bl = Blo + (size_t)z * Bbs;
  float* Cz = C + (size_t)z * Cbs;
  int bm = blockIdx.y * 128, bn = blockIdx.x * 64;
  int w = tid >> 6, lane = tid & 63;
  int wr = w >> 1, wc = w & 1;
  int l15 = lane & 15, l4 = lane >> 4;
  int rsub = lane >> 2;          // row within 16-row chunk
  int qk = (lane & 3) * 8;       // half offset within 32-half row
  f32x4 acc[4][2];
#pragma unroll
  for (int m = 0; m < 4; ++m)
#pragma unroll
    for (int n = 0; n < 2; ++n) acc[m][n] = (f32x4){0.f, 0.f, 0.f, 0.f};
  for (int k0 = 0; k0 < K; k0 += 32) {
    // A panels: 8 chunks each -> chunks {w, w+4}; B panels: 4 chunks -> chunk w
    int ar = w * 16 + rsub;
    int ar2 = ar + 64;
    gll16(Ahi + (size_t)(bm + ar) * K + k0 + qk,  &Ash[w * 16][0]);
    gll16(Ahi + (size_t)(bm + ar2) * K + k0 + qk, &Ash[w * 16 + 64][0]);
    gll16(Alo + (size_t)(bm + ar) * K + k0 + qk,  &Asl[w * 16][0]);
    gll16(Alo + (size_t)(bm + ar2) * K + k0 + qk, &Asl[w * 16 + 64][0]);
    gll16(Bh + (size_t)(bn + ar) * K + k0 + qk,   &Bsh[w * 16][0]);
    gll16(Bl + (size_t)(bn + ar) * K + k0 + qk,   &Bsl[w * 16][0]);
    __syncthreads();
    half8 afh[4], afl[4], bfh[2], bfl[2];
#pragma unroll
    for (int m = 0; m < 4; ++m) {
      afh[m] = *(const half8*)&Ash[wr * 64 + m * 16 + l15][l4 * 8];
      afl[m] = *(const half8*)&Asl[wr * 64 + m * 16 + l15][l4 * 8];
    }
#pragma unroll
    for (int n = 0; n < 2; ++n) {
      bfh[n] = *(const half8*)&Bsh[wc * 32 + n * 16 + l15][l4 * 8];
      bfl[n] = *(const half8*)&Bsl[wc * 32 + n * 16 + l15][l4 * 8];
    }
#pragma unroll
    for (int m = 0; m < 4; ++m)
#pragma unroll
      for (int n = 0; n < 2; ++n) {
        acc[m][n] = __builtin_amdgcn_mfma_f32_16x16x32_f16(afh[m], bfh[n], acc[m][n], 0, 0, 0);
        acc[m][n] = __builtin_amdgcn_mfma_f32_16x16x32_f16(afl[m], bfh[n], acc[m][n], 0, 0, 0);
        acc[m][n] = __builtin_amdgcn_mfma_f32_16x16x32_f16(afh[m], bfl[n], acc[m][n], 0, 0, 0);
      }
    __syncthreads();
  }
#pragma unroll
  for (int m = 0; m < 4; ++m)
#pragma unroll
    for (int n = 0; n < 2; ++n)
#pragma unroll
      for (int rr = 0; rr < 4; ++rr) {
        int row = bm + wr * 64 + m * 16 + l4 * 4 + rr;
        int col = bn + wc * 32 + n * 16 + l15;
        float v = acc[m][n][rr];
        if (bias) v += bias[row];
        Cz[(size_t)row * N + col] = v;
      }
}

// ---------------------------------------------------------------------------
// 64x64-tile variant (4 waves 2x2, wave: 32x32) for M=2048,N=512 dense GEMMs.
__global__ __launch_bounds__(256) void k_mfma_nt3f_64(const _Float16* __restrict__ Ahi,
                                                      const _Float16* __restrict__ Alo,
                                                      const _Float16* __restrict__ Bhi,
                                                      const _Float16* __restrict__ Blo,
                                                      float* __restrict__ C,
                                                      int M, int N, int K) {
  __shared__ __align__(16) _Float16 Ash[64][32];
  __shared__ __align__(16) _Float16 Asl[64][32];
  __shared__ __align__(16) _Float16 Bsh[64][32];
  __shared__ __align__(16) _Float16 Bsl[64][32];
  int tid = threadIdx.x;
  int bm = blockIdx.y * 64, bn = blockIdx.x * 64;
  int w = tid >> 6, lane = tid & 63;
  int wr = w >> 1, wc = w & 1;
  int l15 = lane & 15, l4 = lane >> 4;
  int rsub = lane >> 2;
  int qk = (lane & 3) * 8;
  f32x4 acc[2][2];
#pragma unroll
  for (int m = 0; m < 2; ++m)
#pragma unroll
    for (int n = 0; n < 2; ++n) acc[m][n] = (f32x4){0.f, 0.f, 0.f, 0.f};
  for (int k0 = 0; k0 < K; k0 += 32) {
    int ar = w * 16 + rsub;      // one chunk per wave per panel
    gll16(Ahi + (size_t)(bm + ar) * K + k0 + qk, &Ash[w * 16][0]);
    gll16(Alo + (size_t)(bm + ar) * K + k0 + qk, &Asl[w * 16][0]);
    gll16(Bhi + (size_t)(bn + ar) * K + k0 + qk, &Bsh[w * 16][0]);
    gll16(Blo + (size_t)(bn + ar) * K + k0 + qk, &Bsl[w * 16][0]);
    __syncthreads();
    half8 afh[2], afl[2], bfh[2], bfl[2];
#pragma unroll
    for (int m = 0; m < 2; ++m) {
      afh[m] = *(const half8*)&Ash[wr * 32 + m * 16 + l15][l4 * 8];
      afl[m] = *(const half8*)&Asl[wr * 32 + m * 16 + l15][l4 * 8];
    }
#pragma unroll
    for (int n = 0; n < 2; ++n) {
      bfh[n] = *(const half8*)&Bsh[wc * 32 + n * 16 + l15][l4 * 8];
      bfl[n] = *(const half8*)&Bsl[wc * 32 + n * 16 + l15][l4 * 8];
    }
#pragma unroll
    for (int m = 0; m < 2; ++m)
#pragma unroll
      for (int n = 0; n < 2; ++n) {
        acc[m][n] = __builtin_amdgcn_mfma_f32_16x16x32_f16(afh[m], bfh[n], acc[m][n], 0, 0, 0);
        acc[m][n] = __builtin_amdgcn_mfma_f32_16x16x32_f16(afl[m], bfh[n], acc[m][n], 0, 0, 0);
        acc[m][n] = __builtin_amdgcn_mfma_f32_16x16x32_f16(afh[m], bfl[n], acc[m][n], 0, 0, 0);
      }
    __syncthreads();
  }
#pragma unroll
  for (int m = 0; m < 2; ++m)
#pragma unroll
    for (int n = 0; n < 2; ++n)
#pragma unroll
      for (int rr = 0; rr < 4; ++rr) {
        int row = bm + wr * 32 + m * 16 + l4 * 4 + rr;
        int col = bn + wc * 32 + n * 16 + l15;
        C[(size_t)row * N + col] = acc[m][n][rr];
      }
}

// ---------------------------------------------------------------------------
// 128x128-tile variant (4 waves 2x2, wave: 64x64) for the graph conv.
__global__ __launch_bounds__(256) void k_mfma_nt3f_128(const _Float16* __restrict__ Ahi,
                                                       const _Float16* __restrict__ Alo,
                                                       const _Float16* __restrict__ Bhi,
                                                       const _Float16* __restrict__ Blo,
                                                       float* __restrict__ C,
                                                       int M, int N, int K) {
  __shared__ __align__(16) _Float16 Ash[128][32];
  __shared__ __align__(16) _Float16 Asl[128][32];
  __shared__ __align__(16) _Float16 Bsh[128][32];
  __shared__ __align__(16) _Float16 Bsl[128][32];
  int tid = threadIdx.x;
  int bm = blockIdx.y * 128, bn = blockIdx.x * 128;
  int w = tid >> 6, lane = tid & 63;
  int wr = w >> 1, wc = w & 1;
  int l15 = lane & 15, l4 = lane >> 4;
  int rsub = lane >> 2;
  int qk = (lane & 3) * 8;
  f32x4 acc[4][4];
#pragma unroll
  for (int m = 0; m < 4; ++m)
#pragma unroll
    for (int n = 0; n < 4; ++n) acc[m][n] = (f32x4){0.f, 0.f, 0.f, 0.f};
  for (int k0 = 0; k0 < K; k0 += 32) {
    // each panel has 8 chunks -> chunks {w, w+4}
    int ar = w * 16 + rsub;
    int ar2 = ar + 64;
    gll16(Ahi + (size_t)(bm + ar) * K + k0 + qk,  &Ash[w * 16][0]);
    gll16(Ahi + (size_t)(bm + ar2) * K + k0 + qk, &Ash[w * 16 + 64][0]);
    gll16(Alo + (size_t)(bm + ar) * K + k0 + qk,  &Asl[w * 16][0]);
    gll16(Alo + (size_t)(bm + ar2) * K + k0 + qk, &Asl[w * 16 + 64][0]);
    gll16(Bhi + (size_t)(bn + ar) * K + k0 + qk,  &Bsh[w * 16][0]);
    gll16(Bhi + (size_t)(bn + ar2) * K + k0 + qk, &Bsh[w * 16 + 64][0]);
    gll16(Blo + (size_t)(bn + ar) * K + k0 + qk,  &Bsl[w * 16][0]);
    gll16(Blo + (size_t)(bn + ar2) * K + k0 + qk, &Bsl[w * 16 + 64][0]);
    __syncthreads();
    half8 afh[4], afl[4], bfh[4], bfl[4];
#pragma unroll
    for (int m = 0; m < 4; ++m) {
      afh[m] = *(const half8*)&Ash[wr * 64 + m * 16 + l15][l4 * 8];
      afl[m] = *(const half8*)&Asl[wr * 64 + m * 16 + l15][l4 * 8];
    }
#pragma unroll
    for (int n = 0; n < 4; ++n) {
      bfh[n] = *(const half8*)&Bsh[wc * 64 + n * 16 + l15][l4 * 8];
      bfl[n] = *(const half8*)&Bsl[wc * 64 + n * 16 + l15][l4 * 8];
    }
#pragma unroll
    for (int m = 0; m < 4; ++m)
#pragma unroll
      for (int n = 0; n < 4; ++n) {
        acc[m][n] = __builtin_amdgcn_mfma_f32_16x16x32_f16(afh[m], bfh[n], acc[m][n], 0, 0, 0);
        acc[m][n] = __builtin_amdgcn_mfma_f32_16x16x32_f16(afl[m], bfh[n], acc[m][n], 0, 0, 0);
        acc[m][n] = __builtin_amdgcn_mfma_f32_16x16x32_f16(afh[m], bfl[n], acc[m][n], 0, 0, 0);
      }
    __syncthreads();
  }
#pragma unroll
  for (int m = 0; m < 4; ++m)
#pragma unroll
    for (int n = 0; n < 4; ++n)
#pragma unroll
      for (int rr = 0; rr < 4; ++rr) {
        int row = bm + wr * 64 + m * 16 + l4 * 4 + rr;
        int col = bn + wc * 64 + n * 16 + l15;
        C[(size_t)row * N + col] = acc[m][n][rr];
      }
}

// ---------------------------------------------------------------------------
// Transpose-split e -> eT hi/lo. RAW reinterpret: E4[b,r,h,c] = e_flat[b*1179648
// + r*131072 + h*512 + c]. eT[(b*9+r)*512 + c][h] = E4[b,r,h,c]
__global__ __launch_bounds__(256) void k_eT_split(const float* __restrict__ e,
                                                  _Float16* __restrict__ eth,
                                                  _Float16* __restrict__ etl) {
  __shared__ float tl[64][65];
  int t = threadIdx.x;
  int z = blockIdx.z;          // b*9+r
  int b = z / 9, r = z % 9;
  int h0 = blockIdx.y * 64, c0 = blockIdx.x * 64;
  const float* ez = e + (size_t)b * 1179648 + (size_t)r * 131072;
  for (int k = t; k < 4096; k += 256) {
    int i = k >> 6, j = k & 63;
    tl[i][j] = ez[(size_t)(h0 + i) * 512 + c0 + j];
  }
  __syncthreads();
  for (int k = t; k < 4096; k += 256) {
    int i = k >> 6, j = k & 63;          // i: c-local, j: h-local
    float v = tl[j][i];
    _Float16 hi, lo; split_hl(v, hi, lo);
    size_t o = ((size_t)z * 512 + c0 + i) * 256 + h0 + j;
    eth[o] = hi; etl[o] = lo;
  }
}

// ---------------------------------------------------------------------------
// h2[b,g,c] = sum_r sum_h coef[b,r,g,h] * eT[b,r,c,h]   (NT MFMA, 64x64 tile)
__global__ __launch_bounds__(256) void k_einsum_mfma(const _Float16* __restrict__ Ahi,
                                                     const _Float16* __restrict__ Alo,
                                                     const _Float16* __restrict__ Bhi,
                                                     const _Float16* __restrict__ Blo,
                                                     float* __restrict__ h2) {
  __shared__ __align__(16) _Float16 Ash[64][32];
  __shared__ __align__(16) _Float16 Asl[64][32];
  __shared__ __align__(16) _Float16 Bsh[64][32];
  __shared__ __align__(16) _Float16 Bsl[64][32];
  int tid = threadIdx.x;
  int b = blockIdx.z;
  int bm = blockIdx.y * 64, bn = blockIdx.x * 64;
  int w = tid >> 6, lane = tid & 63;
  int wr = w >> 1, wc = w & 1;
  int l15 = lane & 15, l4 = lane >> 4;
  int rsub = lane >> 2;
  int qk = (lane & 3) * 8;
  f32x4 acc[2][2];
#pragma unroll
  for (int m = 0; m < 2; ++m)
#pragma unroll
    for (int n = 0; n < 2; ++n) acc[m][n] = (f32x4){0.f, 0.f, 0.f, 0.f};
  for (int r = 0; r < 9; ++r) {
    const _Float16* Ah = Ahi + ((size_t)b * 9 + r) * 65536;
    const _Float16* Al = Alo + ((size_t)b * 9 + r) * 65536;
    const _Float16* Bh = Bhi + ((size_t)b * 9 + r) * 131072;
    const _Float16* Bl = Blo + ((size_t)b * 9 + r) * 131072;
    for (int k0 = 0; k0 < 256; k0 += 32) {
      int ar = w * 16 + rsub;
      gll16(Ah + (size_t)(bm + ar) * 256 + k0 + qk, &Ash[w * 16][0]);
      gll16(Al + (size_t)(bm + ar) * 256 + k0 + qk, &Asl[w * 16][0]);
      gll16(Bh + (size_t)(bn + ar) * 256 + k0 + qk, &Bsh[w * 16][0]);
      gll16(Bl + (size_t)(bn + ar) * 256 + k0 + qk, &Bsl[w * 16][0]);
      __syncthreads();
      half8 afh[2], afl[2], bfh[2], bfl[2];
#pragma unroll
      for (int m = 0; m < 2; ++m) {
        afh[m] = *(const half8*)&Ash[wr * 32 + m * 16 + l15][l4 * 8];
        afl[m] = *(const half8*)&Asl[wr * 32 + m * 16 + l15][l4 * 8];
      }
#pragma unroll
      for (int n = 0; n < 2; ++n) {
        bfh[n] = *(const half8*)&Bsh[wc * 32 + n * 16 + l15][l4 * 8];
        bfl[n] = *(const half8*)&Bsl[wc * 32 + n * 16 + l15][l4 * 8];
      }
#pragma unroll
      for (int m = 0; m < 2; ++m)
#pragma unroll
        for (int n = 0; n < 2; ++n) {
          acc[m][n] = __builtin_amdgcn_mfma_f32_16x16x32_f16(afh[m], bfh[n], acc[m][n], 0, 0, 0);
          acc[m][n] = __builtin_amdgcn_mfma_f32_16x16x32_f16(afl[m], bfh[n], acc[m][n], 0, 0, 0);
          acc[m][n] = __builtin_amdgcn_mfma_f32_16x16x32_f16(afh[m], bfl[n], acc[m][n], 0, 0, 0);
        }
      __syncthreads();
    }
  }
#pragma unroll
  for (int m = 0; m < 2; ++m)
#pragma unroll
    for (int n = 0; n < 2; ++n)
#pragma unroll
      for (int rr = 0; rr < 4; ++rr) {
        int row = bm + wr * 32 + m * 16 + l4 * 4 + rr;
        int col = bn + wc * 32 + n * 16 + l15;
        h2[(size_t)b * 131072 + (size_t)row * 512 + col] = acc[m][n][rr];
      }
}

// ---------------------------------------------------------------------------
// BatchNorm1d stats per group g over (B, C); f64 accumulation.
__global__ __launch_bounds__(256) void k_bn_stats(const float* __restrict__ h,
                                                  const float* __restrict__ gamma,
                                                  const float* __restrict__ beta,
                                                  float* __restrict__ bnA,
                                                  float* __restrict__ bnB) {
  __shared__ double ls[256], lq[256];
  int g = blockIdx.x;
  int tid = threadIdx.x;
  double s = 0.0, q = 0.0;
  for (int idx = tid; idx < 4096; idx += 256) {
    int bb = idx >> 9, c = idx & 511;
    double v = (double)h[((size_t)(bb * 256 + g)) * 512 + c];
    s += v; q += v * v;
  }
  ls[tid] = s; lq[tid] = q;
  __syncthreads();
  for (int off = 128; off; off >>= 1) {
    if (tid < off) { ls[tid] += ls[tid + off]; lq[tid] += lq[tid + off]; }
    __syncthreads();
  }
  if (tid == 0) {
    double mean = ls[0] * (1.0 / 4096.0);
    double var = lq[0] * (1.0 / 4096.0) - mean * mean;
    if (var < 0.0) var = 0.0;
    float rstd = (float)rsqrt(var + 1e-5);
    float a = gamma[g] * rstd;
    bnA[g] = a;
    bnB[g] = beta[g] - (float)mean * a;
  }
}

__global__ __launch_bounds__(256) void k_bn_apply_relu_cat(const float* __restrict__ h,
                                                           const float* __restrict__ bnA,
                                                           const float* __restrict__ bnB,
                                                           _Float16* __restrict__ hhi,
                                                           _Float16* __restrict__ hlo) {
  size_t idx = (size_t)blockIdx.x * 256 + threadIdx.x;  // 1,048,576
  int g = (int)((idx >> 9) & 255);
  float y = fmaxf(fmaf(h[idx], bnA[g], bnB[g]), 0.0f);
  _Float16 hi, lo; split_hl(y, hi, lo);
  hhi[idx] = hi; hlo[idx] = lo;
}

__global__ __launch_bounds__(256) void k_bn_apply_res_relu_cat(const float* __restrict__ h,
                                                               const float* __restrict__ bnA,
                                                               const float* __restrict__ bnB,
                                                               float* __restrict__ x,
                                                               _Float16* __restrict__ xhi,
                                                               _Float16* __restrict__ xlo) {
  size_t idx = (size_t)blockIdx.x * 256 + threadIdx.x;  // 1,048,576
  int g = (int)((idx >> 9) & 255);
  float y = fmaxf(fmaf(h[idx], bnA[g], bnB[g]) + x[idx], 0.0f);
  x[idx] = y;
  _Float16 hi, lo; split_hl(y, hi, lo);
  xhi[idx] = hi; xlo[idx] = lo;
}

// ---------------------------------------------------------------------------
// Build xcatT[b][p][c] hi/lo (c<512: unpool scramble of x; c>=512: inp^T).
__global__ __launch_bounds__(256) void k_xcatT(const float* __restrict__ x,
                                               const float* __restrict__ cnt,
                                               const int* __restrict__ gl,
                                               const float* __restrict__ inp,
                                               _Float16* __restrict__ xch,
                                               _Float16* __restrict__ xcl) {
  __shared__ float tl[64][65];
  __shared__ int lab[1024];
  __shared__ float ic[256];
  int t = threadIdx.x;
  int b = blockIdx.y, p0 = blockIdx.x * 64;
  for (int k = t; k < 1024; k += 256) lab[k] = gl[b * 1024 + k];
  if (t < 256) ic[t] = 1.0f / (cnt[b * 256 + t] + 1e-7f);
  __syncthreads();
  for (int pp = 0; pp < 64; ++pp) {
    int p = p0 + pp;
    int p9 = p >> 9, c2 = p & 511;
    const float* xb = x + (size_t)b * 131072 + c2;
    size_t obase = ((size_t)b * 1024 + p) * 1024;
#pragma unroll
    for (int ch = 0; ch < 512; ch += 256) {
      int c = ch + t;
      int g = lab[2 * c + p9];
      float v = xb[(size_t)g * 512] * ic[g];
      _Float16 hi, lo; split_hl(v, hi, lo);
      xch[obase + c] = hi; xcl[obase + c] = lo;
    }
  }
  for (int ct = 0; ct < 512; ct += 64) {
    __syncthreads();
    for (int k = t; k < 4096; k += 256) {
      int i = k >> 6, j = k & 63;
      tl[i][j] = inp[(size_t)b * 524288 + (size_t)(ct + i) * 1024 + p0 + j];
    }
    __syncthreads();
    for (int k = t; k < 4096; k += 256) {
      int i = k >> 6, j = k & 63;
      float v = tl[j][i];
      _Float16 hi, lo; split_hl(v, hi, lo);
      size_t o = ((size_t)b * 1024 + p0 + i) * 1024 + 512 + ct + j;
      xch[o] = hi; xcl[o] = lo;
    }
  }
}

// ---------------------------------------------------------------------------
extern "C" void kernel_launch(void* const* d_in, const int* in_sizes, int n_in,
                              void* d_out, int out_size, void* d_ws, size_t ws_size,
                              hipStream_t stream) {
  const float* inp   = (const float*)d_in[0];
  const int*   gl    = (const int*)d_in[1];
  const float* adj   = (const float*)d_in[2];
  const float* w1    = (const float*)d_in[3];
  const float* wg    = (const float*)d_in[4];
  const float* w2    = (const float*)d_in[5];
  const float* bng   = (const float*)d_in[6];
  const float* bnb   = (const float*)d_in[7];
  const float* convw = (const float*)d_in[8];
  const float* convb = (const float*)d_in[9];
  float* out = (float*)d_out;
  float* ws = (float*)d_ws;

  _Float16* wgchi = (_Float16*)(ws + OFF_WGCH);
  _Float16* wgclo = (_Float16*)(ws + OFF_WGCL);
  _Float16* coefhi = (_Float16*)(ws + OFF_COEFH);
  _Float16* coeflo = (_Float16*)(ws + OFF_COEFL);
  float* x     = ws + OFF_X;
  float* cnt   = ws + OFF_CNT;
  int*   cntI  = (int*)(ws + OFF_CNTI);
  int*   lists = (int*)(ws + OFF_LISTS);
  int*   csrO  = (int*)(ws + OFF_CSRO);
  unsigned short* csrV = (unsigned short*)(ws + OFF_CSRV);
  float* bnA   = ws + OFF_BNA;
  float* bnB   = ws + OFF_BNB;
  _Float16* w1hi = (_Float16*)(ws + OFF_W1H);
  _Float16* w1lo = (_Float16*)(ws + OFF_W1L);
  _Float16* w2hi = (_Float16*)(ws + OFF_W2H);
  _Float16* w2lo = (_Float16*)(ws + OFF_W2L);
  _Float16* cwhi = (_Float16*)(ws + OFF_CWH);
  _Float16* cwlo = (_Float16*)(ws + OFF_CWL);
  _Float16* xhi  = (_Float16*)(ws + OFF_XH);
  _Float16* xlo  = (_Float16*)(ws + OFF_XL);
  _Float16* hhi  = (_Float16*)(ws + OFF_HH);
  _Float16* hlo  = (_Float16*)(ws + OFF_HL);
  float* t2 = ws + OFF_BIG;
  float* e  = ws + OFF_BIG;
  _Float16* eth = (_Float16*)(ws + OFF_BIG + 9437184);
  _Float16* etl = (_Float16*)(ws + OFF_BIG + 14155776);
  _Float16* xch = (_Float16*)(ws + OFF_BIG);
  _Float16* xcl = (_Float16*)(ws + OFF_BIG + 4194304);
  float* ga = ws + OFF_GA;
  float* h1 = ws + OFF_H1;
  float* h2 = ws + OFF_H2;

  hipMemsetAsync(cntI, 0, 2048 * 4, stream);

  k_collapse_wg<<<27648, 256, 0, stream>>>(wg, wgchi, wgclo);
  k_split_pair<<<3072, 256, 0, stream>>>(w1, w1hi, w1lo);
  k_split_pair<<<3072, 256, 0, stream>>>(w2, w2hi, w2lo);
  k_split_pair<<<2048, 256, 0, stream>>>(convw, cwhi, cwlo);
  k_lists<<<32, 256, 0, stream>>>(gl, cntI, lists);
  k_cntf<<<8, 256, 0, stream>>>(cntI, cnt);
  k_csr<<<1, 256, 0, stream>>>(cntI, lists, csrO, csrV);
  k_t2_gather<<<dim3(128, 9), 256, 0, stream>>>(adj, csrO, csrV, t2);
  k_ga_gather<<<1152, 256, 0, stream>>>(t2, cntI, lists, ga);
  k_coef<<<18432, 256, 0, stream>>>(ga, coefhi, coeflo);
  k_pool_csr<<<512, 256, 0, stream>>>(inp, csrO, csrV, x, xhi, xlo);

  for (int i = 0; i < 3; ++i) {
    // dense1: h1 = x @ w1^T   (64x64 tile -> 256 blocks)
    k_mfma_nt3f_64<<<dim3(8, 32), 256, 0, stream>>>(xhi, xlo, w1hi + (size_t)i * 262144,
        w1lo + (size_t)i * 262144, h1, 2048, 512, 512);
    k_bn_stats<<<256, 256, 0, stream>>>(h1, bng + (i * 3 + 0) * 256, bnb + (i * 3 + 0) * 256, bnA, bnB);
    k_bn_apply_relu_cat<<<4096, 256, 0, stream>>>(h1, bnA, bnB, hhi, hlo);
    // graph conv: e = h @ wgc^T  (128x128 tile -> 576 blocks)
    k_mfma_nt3f_128<<<dim3(36, 16), 256, 0, stream>>>(hhi, hlo, wgchi + (size_t)i * 2359296,
        wgclo + (size_t)i * 2359296, e, 2048, 4608, 512);
    // coef einsum via MFMA
    k_eT_split<<<dim3(8, 4, 72), 256, 0, stream>>>(e, eth, etl);
    k_einsum_mfma<<<dim3(8, 4, 8), 256, 0, stream>>>(coefhi, coeflo, eth, etl, h2);
    k_bn_stats<<<256, 256, 0, stream>>>(h2, bng + (i * 3 + 1) * 256, bnb + (i * 3 + 1) * 256, bnA, bnB);
    k_bn_apply_relu_cat<<<4096, 256, 0, stream>>>(h2, bnA, bnB, hhi, hlo);
    // dense2: h1 = h @ w2^T
    k_mfma_nt3f_64<<<dim3(8, 32), 256, 0, stream>>>(hhi, hlo, w2hi + (size_t)i * 262144,
        w2lo + (size_t)i * 262144, h1, 2048, 512, 512);
    k_bn_stats<<<256, 256, 0, stream>>>(h1, bng + (i * 3 + 2) * 256, bnb + (i * 3 + 2) * 256, bnA, bnB);
    k_bn_apply_res_relu_cat<<<4096, 256, 0, stream>>>(h1, bnA, bnB, x, xhi, xlo);
  }

  k_xcatT<<<dim3(16, 8), 256, 0, stream>>>(x, cnt, gl, inp, xch, xcl);
  // out[b] = convw @ xcatT[b]^T + bias
  k_mfma_nt3f<<<dim3(16, 4, 8), 256, 0, stream>>>(cwhi, cwlo, xch, xcl, out, convb,
      512, 1024, 1024, 1048576, 524288);
}

// Round 2
// 664.891 us; speedup vs baseline: 1.1625x; 1.1285x over previous
//
#include <hip/hip_runtime.h>
#include <math.h>

// Problem constants: B=8, C=512, H=W=32, N=1024, G=256, R=9
using half8 = __attribute__((ext_vector_type(8))) _Float16;
using f32x4 = __attribute__((ext_vector_type(4))) float;

// Workspace layout (f32 slots)
static constexpr size_t OFF_WGCH  = 0;           // 3*4608*512 halfs
static constexpr size_t OFF_WGCL  = 3538944;
static constexpr size_t OFF_COEF  = 7077888;     // (unused f32 slot kept for layout stability)
static constexpr size_t OFF_COEFH = 11796480;    // 4718592 halfs
static constexpr size_t OFF_COEFL = 14155776;
static constexpr size_t OFF_X     = 16515072;    // 1048576 f32
static constexpr size_t OFF_CNT   = 17563648;    // 2048 f32 (unused)
static constexpr size_t OFF_CNTI  = 17565696;    // 2048 int
static constexpr size_t OFF_LISTS = 17567744;    // 98304 int
static constexpr size_t OFF_CSRO  = 17666048;    // 2049 int (pad to 2304)
static constexpr size_t OFF_CSRV  = 17668352;    // 8192 u16
static constexpr size_t OFF_BNA   = 17672448;    // 256 (unused)
static constexpr size_t OFF_BNB   = 17672704;    // 256 (unused)
static constexpr size_t OFF_W1H   = 17672960;    // 3*512*512 halfs
static constexpr size_t OFF_W1L   = 18066176;
static constexpr size_t OFF_W2H   = 18459392;
static constexpr size_t OFF_W2L   = 18852608;
static constexpr size_t OFF_CWH   = 19245824;    // 512*1024 halfs
static constexpr size_t OFF_CWL   = 19507968;
static constexpr size_t OFF_XH    = 19770112;    // 2048*512 halfs
static constexpr size_t OFF_XL    = 20294400;
static constexpr size_t OFF_HH    = 20818688;
static constexpr size_t OFF_HL    = 21342976;
static constexpr size_t OFF_BIG   = 21867264;    // 18874368 f32 region
static constexpr size_t OFF_GA    = 40741632;    // 4718592 f32; h1/h2 alias after coef
static constexpr size_t OFF_H1    = OFF_GA;
static constexpr size_t OFF_H2    = OFF_GA + 1048576;

__device__ inline void split_hl(float v, _Float16& hi, _Float16& lo) {
  hi = (_Float16)v;
  lo = (_Float16)(v - (float)hi);
}

// Direct global->LDS DMA, 16 B per lane. LDS dest = wave-uniform base + lane*16.
__device__ inline void gll16(const void* g, void* l) {
  __builtin_amdgcn_global_load_lds(
      (__attribute__((address_space(1))) void*)(size_t)g,
      (__attribute__((address_space(3))) void*)(size_t)l, 16, 0, 0);
}

// ---------------------------------------------------------------------------
// wgc[i][j][c] = sum_r wg[i][j][r*512+c] -> fp16 hi/lo
__global__ __launch_bounds__(256) void k_collapse_wg(const float* __restrict__ wg,
                                                     _Float16* __restrict__ whi,
                                                     _Float16* __restrict__ wlo) {
  size_t idx = (size_t)blockIdx.x * 256 + threadIdx.x;   // 3*4608*512
  size_t i = idx / (4608u * 512u);
  size_t rem = idx % (4608u * 512u);
  size_t j = rem / 512u, c = rem % 512u;
  const float* p = wg + i * 4608ull * 4608ull + j * 4608ull + c;
  float s = 0.f;
#pragma unroll
  for (int r = 0; r < 9; ++r) s += p[r * 512];
  _Float16 hi, lo; split_hl(s, hi, lo);
  whi[idx] = hi; wlo[idx] = lo;
}

// Merged hi/lo split for w1, w2, convw in one dispatch.
__global__ __launch_bounds__(256) void k_split3(const float* __restrict__ w1,
                                                const float* __restrict__ w2,
                                                const float* __restrict__ cw,
                                                _Float16* __restrict__ w1h, _Float16* __restrict__ w1l,
                                                _Float16* __restrict__ w2h, _Float16* __restrict__ w2l,
                                                _Float16* __restrict__ cwh, _Float16* __restrict__ cwl) {
  size_t idx = (size_t)blockIdx.x * 256 + threadIdx.x;   // 2097152 total
  const float* s; _Float16 *H, *L; size_t o;
  if (idx < 786432) { s = w1; H = w1h; L = w1l; o = idx; }
  else if (idx < 1572864) { s = w2; H = w2h; L = w2l; o = idx - 786432; }
  else { s = cw; H = cwh; L = cwl; o = idx - 1572864; }
  _Float16 hi, lo; split_hl(s[o], hi, lo);
  H[o] = hi; L[o] = lo;
}

// ---------------------------------------------------------------------------
__global__ __launch_bounds__(256) void k_lists(const int* __restrict__ gl,
                                               int* __restrict__ cntI,
                                               int* __restrict__ lists) {
  int idx = blockIdx.x * 256 + threadIdx.x;  // 8192
  int b = idx >> 10, n = idx & 1023;
  int h = gl[idx];
  int pos = atomicAdd(&cntI[b * 256 + h], 1);
  if (pos < 48) lists[(b * 256 + h) * 48 + pos] = n;
}

// Build CSR: csr_off[2049] (int), csr_val (u16 n-indices grouped by bg)
__global__ __launch_bounds__(256) void k_csr(const int* __restrict__ cntI,
                                             const int* __restrict__ lists,
                                             int* __restrict__ csr_off,
                                             unsigned short* __restrict__ csr_val) {
  __shared__ int wsum[256];
  __shared__ int tot[257];
  int t = threadIdx.x;
  int base = t * 8;
  int loc[8]; int s = 0;
#pragma unroll
  for (int i = 0; i < 8; ++i) {
    int c = cntI[base + i]; if (c > 48) c = 48;
    loc[i] = s; s += c;
  }
  wsum[t] = s;
  __syncthreads();
  if (t == 0) {
    int a = 0;
    for (int i = 0; i < 256; ++i) { tot[i] = a; a += wsum[i]; }
    tot[256] = a;
  }
  __syncthreads();
  int off0 = tot[t];
#pragma unroll
  for (int i = 0; i < 8; ++i) {
    int bg = base + i;
    int o = off0 + loc[i];
    csr_off[bg] = o;
    int c = cntI[bg]; if (c > 48) c = 48;
    for (int j = 0; j < c; ++j)
      csr_val[o + j] = (unsigned short)(lists[bg * 48 + j] & 1023);
  }
  if (t == 0) csr_off[2048] = tot[256];
}

// ---------------------------------------------------------------------------
// t2[(r*1024+n)*2048 + bg] = sum_{m in members(bg)} adj[r,n,m]
__global__ __launch_bounds__(256) void k_t2_gather(const float* __restrict__ adj,
                                                   const int* __restrict__ csr_off,
                                                   const unsigned short* __restrict__ csr_val,
                                                   float* __restrict__ t2) {
  __shared__ float rows[8][1032];           // 33 KB -> 4 blocks/CU
  int t = threadIdx.x;
  int r = blockIdx.y;
  int n0 = blockIdx.x * 8;
  const float4* src = (const float4*)(adj + ((size_t)r * 1024 + n0) * 1024);
  for (int k = t; k < 2048; k += 256) {
    float4 v = src[k];
    int n = k >> 8;
    int m = (k & 255) << 2;
    *(float4*)&rows[n][m] = v;   // (n*1032+m)*4 bytes, 16B-aligned
  }
  __syncthreads();
#pragma unroll
  for (int j = 0; j < 8; ++j) {
    int bg = j * 256 + t;
    int o0 = csr_off[bg], o1 = csr_off[bg + 1];
    float s[8] = {0.f, 0.f, 0.f, 0.f, 0.f, 0.f, 0.f, 0.f};
    for (int i = o0; i < o1; ++i) {
      int m = csr_val[i];
#pragma unroll
      for (int n = 0; n < 8; ++n) s[n] += rows[n][m];   // 8 independent reads
    }
    size_t base = ((size_t)r * 1024 + n0) * 2048 + bg;
#pragma unroll
    for (int n = 0; n < 8; ++n) t2[base + (size_t)n * 2048] = s[n];
  }
}

// ---------------------------------------------------------------------------
// ga[b,r,g,h] = sum_{n in members(b,h)} t2[(r*1024+n)*2048 + b*256+g]
__global__ __launch_bounds__(256) void k_ga_gather(const float* __restrict__ t2,
                                                   const int* __restrict__ cntI,
                                                   const int* __restrict__ lists,
                                                   float* __restrict__ ga) {
  __shared__ float tile[256 * 17];
  int t = threadIdx.x;            // g
  int h16 = blockIdx.x & 15;
  int r = (blockIdx.x >> 4) % 9;
  int b = (blockIdx.x >> 4) / 9;
  const float* t2b = t2 + (size_t)r * 1024 * 2048 + b * 256 + t;
  for (int hh = 0; hh < 16; ++hh) {
    int h = h16 * 16 + hh;
    int cnt = cntI[b * 256 + h]; if (cnt > 48) cnt = 48;
    const int* lst = lists + (b * 256 + h) * 48;
    float acc = 0.f;
    for (int i = 0; i < cnt; ++i) acc += t2b[(size_t)lst[i] * 2048];
    tile[t * 17 + hh] = acc;
  }
  __syncthreads();
  size_t base = ((size_t)(b * 9 + r) * 256) * 256 + h16 * 16;
  for (int j = 0; j < 16; ++j) {
    int flat = j * 256 + t;
    int g = flat >> 4, hh = flat & 15;
    ga[base + (size_t)g * 256 + hh] = tile[g * 17 + hh];
  }
}

// ---------------------------------------------------------------------------
// coef[b,r,g,h] = num / (sum_h ga[b,r,g,h] + 1); writes fp16 hi/lo directly.
__global__ __launch_bounds__(256) void k_coef(const float* __restrict__ ga,
                                              _Float16* __restrict__ chi,
                                              _Float16* __restrict__ clo) {
  __shared__ float red[256];
  int tid = threadIdx.x;
  int g = blockIdx.x & 255;
  int r = (blockIdx.x >> 8) % 9;
  int b = (blockIdx.x >> 8) / 9;
  size_t base = (((size_t)b * 9 + r) * 256 + g) * 256;
  float v = ga[base + tid];
  red[tid] = v;
  __syncthreads();
  for (int off = 128; off; off >>= 1) {
    if (tid < off) red[tid] += red[tid + off];
    __syncthreads();
  }
  float denom = red[0] + 1.0f;
  float num;
  if (r == 3) {
    num = v;
  } else {
    float vf = ga[((((size_t)(7 - b)) * 9 + r) * 256 + g) * 256 + tid];
    num = fmaxf(v - vf, 0.f);
  }
  float c = num / denom;
  _Float16 hi, lo; split_hl(c, hi, lo);
  chi[base + tid] = hi; clo[base + tid] = lo;
}

// ---------------------------------------------------------------------------
// Pool via CSR gather; also emits x hi/lo halves (fused split).
__global__ __launch_bounds__(256) void k_pool_csr(const float* __restrict__ inp,
                                                  const int* __restrict__ csr_off,
                                                  const unsigned short* __restrict__ csr_val,
                                                  float* __restrict__ x,
                                                  _Float16* __restrict__ xh,
                                                  _Float16* __restrict__ xl) {
  __shared__ float rows[8][1032];         // 33 KB
  __shared__ int offs[257];
  __shared__ unsigned short vals[1024];
  int t = threadIdx.x;
  int b = blockIdx.x >> 6, cch = blockIdx.x & 63;
  const float4* src = (const float4*)(inp + (size_t)b * 524288 + (size_t)cch * 8 * 1024);
  for (int k = t; k < 2048; k += 256) {
    float4 v = src[k];
    int c = k >> 8;
    int m = (k & 255) << 2;
    *(float4*)&rows[c][m] = v;
  }
  for (int k = t; k < 257; k += 256) offs[k] = csr_off[b * 256 + k];
  __syncthreads();
  int vbase = offs[0];
  int nv = offs[256] - vbase;
  for (int k = t; k < nv; k += 256) vals[k] = csr_val[vbase + k];
  __syncthreads();
  int g = t;
  int o0 = offs[g] - vbase, o1 = offs[g + 1] - vbase;
  float s[8] = {0.f, 0.f, 0.f, 0.f, 0.f, 0.f, 0.f, 0.f};
  for (int i = o0; i < o1; ++i) {
    int n = vals[i];
#pragma unroll
    for (int c = 0; c < 8; ++c) s[c] += rows[c][n];
  }
  const float sc = 1.0f / (1.0f + 1e-7f);
  size_t xbase = ((size_t)b * 256 + g) * 512 + cch * 8;
#pragma unroll
  for (int c = 0; c < 8; ++c) {
    float v = s[c] * sc;
    x[xbase + c] = v;
    _Float16 hi, lo; split_hl(v, hi, lo);
    xh[xbase + c] = hi; xl[xbase + c] = lo;
  }
}

// ---------------------------------------------------------------------------
// Fused hi/lo NT MFMA, 128(M) x 64(N) tile, 4 waves 2x2 (wave: 64x32).
// Double-buffered gll16 staging: one barrier per K-step; next tile's loads
// fly during compute, drained by the compiler's vmcnt(0)-before-barrier.
__global__ __launch_bounds__(256) void k_mfma_nt3f(const _Float16* __restrict__ Ahi,
                                                   const _Float16* __restrict__ Alo,
                                                   const _Float16* __restrict__ Bhi,
                                                   const _Float16* __restrict__ Blo,
                                                   float* __restrict__ C,
                                                   const float* __restrict__ bias,
                                                   int M, int N, int K,
                                                   size_t Bbs, size_t Cbs) {
  __shared__ __align__(16) _Float16 Ash[2][128][32];
  __shared__ __align__(16) _Float16 Asl[2][128][32];
  __shared__ __align__(16) _Float16 Bsh[2][64][32];
  __shared__ __align__(16) _Float16 Bsl[2][64][32];
  int tid = threadIdx.x;
  int z = blockIdx.z;
  const _Float16* Bh = Bhi + (size_t)z * Bbs;
  const _Float16* Bl = Blo + (size_t)z * Bbs;
  float* Cz = C + (size_t)z * Cbs;
  int bm = blockIdx.y * 128, bn = blockIdx.x * 64;
  int w = tid >> 6, lane = tid & 63;
  int wr = w >> 1, wc = w & 1;
  int l15 = lane & 15, l4 = lane >> 4;
  int rsub = lane >> 2;          // row within 16-row chunk
  int qk = (lane & 3) * 8;       // half offset within 32-half row
  int ar = w * 16 + rsub;
  int ar2 = ar + 64;
  f32x4 acc[4][2];
#pragma unroll
  for (int m = 0; m < 4; ++m)
#pragma unroll
    for (int n = 0; n < 2; ++n) acc[m][n] = (f32x4){0.f, 0.f, 0.f, 0.f};
  auto STG = [&](int bi, int k0) {
    gll16(Ahi + (size_t)(bm + ar) * K + k0 + qk,  &Ash[bi][w * 16][0]);
    gll16(Ahi + (size_t)(bm + ar2) * K + k0 + qk, &Ash[bi][w * 16 + 64][0]);
    gll16(Alo + (size_t)(bm + ar) * K + k0 + qk,  &Asl[bi][w * 16][0]);
    gll16(Alo + (size_t)(bm + ar2) * K + k0 + qk, &Asl[bi][w * 16 + 64][0]);
    gll16(Bh + (size_t)(bn + ar) * K + k0 + qk,   &Bsh[bi][w * 16][0]);
    gll16(Bl + (size_t)(bn + ar) * K + k0 + qk,   &Bsl[bi][w * 16][0]);
  };
  int nt = K >> 5;
  STG(0, 0);
  int cur = 0;
  for (int t = 0; t < nt; ++t, cur ^= 1) {
    __syncthreads();                    // tile t landed; buf cur^1 free
    if (t + 1 < nt) STG(cur ^ 1, (t + 1) << 5);
    half8 afh[4], afl[4], bfh[2], bfl[2];
#pragma unroll
    for (int m = 0; m < 4; ++m) {
      afh[m] = *(const half8*)&Ash[cur][wr * 64 + m * 16 + l15][l4 * 8];
      afl[m] = *(const half8*)&Asl[cur][wr * 64 + m * 16 + l15][l4 * 8];
    }
#pragma unroll
    for (int n = 0; n < 2; ++n) {
      bfh[n] = *(const half8*)&Bsh[cur][wc * 32 + n * 16 + l15][l4 * 8];
      bfl[n] = *(const half8*)&Bsl[cur][wc * 32 + n * 16 + l15][l4 * 8];
    }
#pragma unroll
    for (int m = 0; m < 4; ++m)
#pragma unroll
      for (int n = 0; n < 2; ++n) {
        acc[m][n] = __builtin_amdgcn_mfma_f32_16x16x32_f16(afh[m], bfh[n], acc[m][n], 0, 0, 0);
        acc[m][n] = __builtin_amdgcn_mfma_f32_16x16x32_f16(afl[m], bfh[n], acc[m][n], 0, 0, 0);
        acc[m][n] = __builtin_amdgcn_mfma_f32_16x16x32_f16(afh[m], bfl[n], acc[m][n], 0, 0, 0);
      }
  }
#pragma unroll
  for (int m = 0; m < 4; ++m)
#pragma unroll
    for (int n = 0; n < 2; ++n)
#pragma unroll
      for (int rr = 0; rr < 4; ++rr) {
        int row = bm + wr * 64 + m * 16 + l4 * 4 + rr;
        int col = bn + wc * 32 + n * 16 + l15;
        float v = acc[m][n][rr];
        if (bias) v += bias[row];
        Cz[(size_t)row * N + col] = v;
      }
}

// ---------------------------------------------------------------------------
// 64x64-tile variant (4 waves 2x2, wave: 32x32), double-buffered.
__global__ __launch_bounds__(256) void k_mfma_nt3f_64(const _Float16* __restrict__ Ahi,
                                                      const _Float16* __restrict__ Alo,
                                                      const _Float16* __restrict__ Bhi,
                                                      const _Float16* __restrict__ Blo,
                                                      float* __restrict__ C,
                                                      int M, int N, int K) {
  __shared__ __align__(16) _Float16 Ash[2][64][32];
  __shared__ __align__(16) _Float16 Asl[2][64][32];
  __shared__ __align__(16) _Float16 Bsh[2][64][32];
  __shared__ __align__(16) _Float16 Bsl[2][64][32];
  int tid = threadIdx.x;
  int bm = blockIdx.y * 64, bn = blockIdx.x * 64;
  int w = tid >> 6, lane = tid & 63;
  int wr = w >> 1, wc = w & 1;
  int l15 = lane & 15, l4 = lane >> 4;
  int rsub = lane >> 2;
  int qk = (lane & 3) * 8;
  int ar = w * 16 + rsub;
  f32x4 acc[2][2];
#pragma unroll
  for (int m = 0; m < 2; ++m)
#pragma unroll
    for (int n = 0; n < 2; ++n) acc[m][n] = (f32x4){0.f, 0.f, 0.f, 0.f};
  auto STG = [&](int bi, int k0) {
    gll16(Ahi + (size_t)(bm + ar) * K + k0 + qk, &Ash[bi][w * 16][0]);
    gll16(Alo + (size_t)(bm + ar) * K + k0 + qk, &Asl[bi][w * 16][0]);
    gll16(Bhi + (size_t)(bn + ar) * K + k0 + qk, &Bsh[bi][w * 16][0]);
    gll16(Blo + (size_t)(bn + ar) * K + k0 + qk, &Bsl[bi][w * 16][0]);
  };
  int nt = K >> 5;
  STG(0, 0);
  int cur = 0;
  for (int t = 0; t < nt; ++t, cur ^= 1) {
    __syncthreads();
    if (t + 1 < nt) STG(cur ^ 1, (t + 1) << 5);
    half8 afh[2], afl[2], bfh[2], bfl[2];
#pragma unroll
    for (int m = 0; m < 2; ++m) {
      afh[m] = *(const half8*)&Ash[cur][wr * 32 + m * 16 + l15][l4 * 8];
      afl[m] = *(const half8*)&Asl[cur][wr * 32 + m * 16 + l15][l4 * 8];
    }
#pragma unroll
    for (int n = 0; n < 2; ++n) {
      bfh[n] = *(const half8*)&Bsh[cur][wc * 32 + n * 16 + l15][l4 * 8];
      bfl[n] = *(const half8*)&Bsl[cur][wc * 32 + n * 16 + l15][l4 * 8];
    }
#pragma unroll
    for (int m = 0; m < 2; ++m)
#pragma unroll
      for (int n = 0; n < 2; ++n) {
        acc[m][n] = __builtin_amdgcn_mfma_f32_16x16x32_f16(afh[m], bfh[n], acc[m][n], 0, 0, 0);
        acc[m][n] = __builtin_amdgcn_mfma_f32_16x16x32_f16(afl[m], bfh[n], acc[m][n], 0, 0, 0);
        acc[m][n] = __builtin_amdgcn_mfma_f32_16x16x32_f16(afh[m], bfl[n], acc[m][n], 0, 0, 0);
      }
  }
#pragma unroll
  for (int m = 0; m < 2; ++m)
#pragma unroll
    for (int n = 0; n < 2; ++n)
#pragma unroll
      for (int rr = 0; rr < 4; ++rr) {
        int row = bm + wr * 32 + m * 16 + l4 * 4 + rr;
        int col = bn + wc * 32 + n * 16 + l15;
        C[(size_t)row * N + col] = acc[m][n][rr];
      }
}

// ---------------------------------------------------------------------------
// 128x128-tile variant (4 waves 2x2, wave: 64x64), double-buffered (64 KB LDS).
__global__ __launch_bounds__(256) void k_mfma_nt3f_128(const _Float16* __restrict__ Ahi,
                                                       const _Float16* __restrict__ Alo,
                                                       const _Float16* __restrict__ Bhi,
                                                       const _Float16* __restrict__ Blo,
                                                       float* __restrict__ C,
                                                       int M, int N, int K) {
  __shared__ __align__(16) _Float16 Ash[2][128][32];
  __shared__ __align__(16) _Float16 Asl[2][128][32];
  __shared__ __align__(16) _Float16 Bsh[2][128][32];
  __shared__ __align__(16) _Float16 Bsl[2][128][32];
  int tid = threadIdx.x;
  int bm = blockIdx.y * 128, bn = blockIdx.x * 128;
  int w = tid >> 6, lane = tid & 63;
  int wr = w >> 1, wc = w & 1;
  int l15 = lane & 15, l4 = lane >> 4;
  int rsub = lane >> 2;
  int qk = (lane & 3) * 8;
  int ar = w * 16 + rsub;
  int ar2 = ar + 64;
  f32x4 acc[4][4];
#pragma unroll
  for (int m = 0; m < 4; ++m)
#pragma unroll
    for (int n = 0; n < 4; ++n) acc[m][n] = (f32x4){0.f, 0.f, 0.f, 0.f};
  auto STG = [&](int bi, int k0) {
    gll16(Ahi + (size_t)(bm + ar) * K + k0 + qk,  &Ash[bi][w * 16][0]);
    gll16(Ahi + (size_t)(bm + ar2) * K + k0 + qk, &Ash[bi][w * 16 + 64][0]);
    gll16(Alo + (size_t)(bm + ar) * K + k0 + qk,  &Asl[bi][w * 16][0]);
    gll16(Alo + (size_t)(bm + ar2) * K + k0 + qk, &Asl[bi][w * 16 + 64][0]);
    gll16(Bhi + (size_t)(bn + ar) * K + k0 + qk,  &Bsh[bi][w * 16][0]);
    gll16(Bhi + (size_t)(bn + ar2) * K + k0 + qk, &Bsh[bi][w * 16 + 64][0]);
    gll16(Blo + (size_t)(bn + ar) * K + k0 + qk,  &Bsl[bi][w * 16][0]);
    gll16(Blo + (size_t)(bn + ar2) * K + k0 + qk, &Bsl[bi][w * 16 + 64][0]);
  };
  int nt = K >> 5;
  STG(0, 0);
  int cur = 0;
  for (int t = 0; t < nt; ++t, cur ^= 1) {
    __syncthreads();
    if (t + 1 < nt) STG(cur ^ 1, (t + 1) << 5);
    half8 afh[4], afl[4], bfh[4], bfl[4];
#pragma unroll
    for (int m = 0; m < 4; ++m) {
      afh[m] = *(const half8*)&Ash[cur][wr * 64 + m * 16 + l15][l4 * 8];
      afl[m] = *(const half8*)&Asl[cur][wr * 64 + m * 16 + l15][l4 * 8];
    }
#pragma unroll
    for (int n = 0; n < 4; ++n) {
      bfh[n] = *(const half8*)&Bsh[cur][wc * 64 + n * 16 + l15][l4 * 8];
      bfl[n] = *(const half8*)&Bsl[cur][wc * 64 + n * 16 + l15][l4 * 8];
    }
#pragma unroll
    for (int m = 0; m < 4; ++m)
#pragma unroll
      for (int n = 0; n < 4; ++n) {
        acc[m][n] = __builtin_amdgcn_mfma_f32_16x16x32_f16(afh[m], bfh[n], acc[m][n], 0, 0, 0);
        acc[m][n] = __builtin_amdgcn_mfma_f32_16x16x32_f16(afl[m], bfh[n], acc[m][n], 0, 0, 0);
        acc[m][n] = __builtin_amdgcn_mfma_f32_16x16x32_f16(afh[m], bfl[n], acc[m][n], 0, 0, 0);
      }
  }
#pragma unroll
  for (int m = 0; m < 4; ++m)
#pragma unroll
    for (int n = 0; n < 4; ++n)
#pragma unroll
      for (int rr = 0; rr < 4; ++rr) {
        int row = bm + wr * 64 + m * 16 + l4 * 4 + rr;
        int col = bn + wc * 64 + n * 16 + l15;
        C[(size_t)row * N + col] = acc[m][n][rr];
      }
}

// ---------------------------------------------------------------------------
// Transpose-split e -> eT hi/lo.
__global__ __launch_bounds__(256) void k_eT_split(const float* __restrict__ e,
                                                  _Float16* __restrict__ eth,
                                                  _Float16* __restrict__ etl) {
  __shared__ float tl[64][65];
  int t = threadIdx.x;
  int z = blockIdx.z;          // b*9+r
  int b = z / 9, r = z % 9;
  int h0 = blockIdx.y * 64, c0 = blockIdx.x * 64;
  const float* ez = e + (size_t)b * 1179648 + (size_t)r * 131072;
  for (int k = t; k < 4096; k += 256) {
    int i = k >> 6, j = k & 63;
    tl[i][j] = ez[(size_t)(h0 + i) * 512 + c0 + j];
  }
  __syncthreads();
  for (int k = t; k < 4096; k += 256) {
    int i = k >> 6, j = k & 63;          // i: c-local, j: h-local
    float v = tl[j][i];
    _Float16 hi, lo; split_hl(v, hi, lo);
    size_t o = ((size_t)z * 512 + c0 + i) * 256 + h0 + j;
    eth[o] = hi; etl[o] = lo;
  }
}

// ---------------------------------------------------------------------------
// h2[b,g,c] = sum_r sum_h coef[b,r,g,h] * eT[b,r,c,h]  (NT MFMA, 64x64 tile),
// double-buffered over the flattened (r, k0) loop (72 steps).
__global__ __launch_bounds__(256) void k_einsum_mfma(const _Float16* __restrict__ Ahi,
                                                     const _Float16* __restrict__ Alo,
                                                     const _Float16* __restrict__ Bhi,
                                                     const _Float16* __restrict__ Blo,
                                                     float* __restrict__ h2) {
  __shared__ __align__(16) _Float16 Ash[2][64][32];
  __shared__ __align__(16) _Float16 Asl[2][64][32];
  __shared__ __align__(16) _Float16 Bsh[2][64][32];
  __shared__ __align__(16) _Float16 Bsl[2][64][32];
  int tid = threadIdx.x;
  int b = blockIdx.z;
  int bm = blockIdx.y * 64, bn = blockIdx.x * 64;
  int w = tid >> 6, lane = tid & 63;
  int wr = w >> 1, wc = w & 1;
  int l15 = lane & 15, l4 = lane >> 4;
  int rsub = lane >> 2;
  int qk = (lane & 3) * 8;
  int ar = w * 16 + rsub;
  f32x4 acc[2][2];
#pragma unroll
  for (int m = 0; m < 2; ++m)
#pragma unroll
    for (int n = 0; n < 2; ++n) acc[m][n] = (f32x4){0.f, 0.f, 0.f, 0.f};
  auto STG = [&](int bi, int kk) {
    int r = kk >> 3, k0 = (kk & 7) << 5;
    const _Float16* Ah = Ahi + ((size_t)b * 9 + r) * 65536 + (size_t)(bm + ar) * 256 + k0 + qk;
    const _Float16* Al = Alo + ((size_t)b * 9 + r) * 65536 + (size_t)(bm + ar) * 256 + k0 + qk;
    const _Float16* Bh = Bhi + ((size_t)b * 9 + r) * 131072 + (size_t)(bn + ar) * 256 + k0 + qk;
    const _Float16* Bl = Blo + ((size_t)b * 9 + r) * 131072 + (size_t)(bn + ar) * 256 + k0 + qk;
    gll16(Ah, &Ash[bi][w * 16][0]);
    gll16(Al, &Asl[bi][w * 16][0]);
    gll16(Bh, &Bsh[bi][w * 16][0]);
    gll16(Bl, &Bsl[bi][w * 16][0]);
  };
  STG(0, 0);
  int cur = 0;
  for (int kk = 0; kk < 72; ++kk, cur ^= 1) {
    __syncthreads();
    if (kk + 1 < 72) STG(cur ^ 1, kk + 1);
    half8 afh[2], afl[2], bfh[2], bfl[2];
#pragma unroll
    for (int m = 0; m < 2; ++m) {
      afh[m] = *(const half8*)&Ash[cur][wr * 32 + m * 16 + l15][l4 * 8];
      afl[m] = *(const half8*)&Asl[cur][wr * 32 + m * 16 + l15][l4 * 8];
    }
#pragma unroll
    for (int n = 0; n < 2; ++n) {
      bfh[n] = *(const half8*)&Bsh[cur][wc * 32 + n * 16 + l15][l4 * 8];
      bfl[n] = *(const half8*)&Bsl[cur][wc * 32 + n * 16 + l15][l4 * 8];
    }
#pragma unroll
    for (int m = 0; m < 2; ++m)
#pragma unroll
      for (int n = 0; n < 2; ++n) {
        acc[m][n] = __builtin_amdgcn_mfma_f32_16x16x32_f16(afh[m], bfh[n], acc[m][n], 0, 0, 0);
        acc[m][n] = __builtin_amdgcn_mfma_f32_16x16x32_f16(afl[m], bfh[n], acc[m][n], 0, 0, 0);
        acc[m][n] = __builtin_amdgcn_mfma_f32_16x16x32_f16(afh[m], bfl[n], acc[m][n], 0, 0, 0);
      }
  }
#pragma unroll
  for (int m = 0; m < 2; ++m)
#pragma unroll
    for (int n = 0; n < 2; ++n)
#pragma unroll
      for (int rr = 0; rr < 4; ++rr) {
        int row = bm + wr * 32 + m * 16 + l4 * 4 + rr;
        int col = bn + wc * 32 + n * 16 + l15;
        h2[(size_t)b * 131072 + (size_t)row * 512 + col] = acc[m][n][rr];
      }
}

// ---------------------------------------------------------------------------
// Fused BatchNorm1d: per-group stats (f64, identical reduction order to the
// old k_bn_stats) + apply(+residual) + relu + hi/lo split, values kept in
// registers between the two phases. res=0: y=relu(bn(h)); res=1: y=relu(bn(h)+x),
// x updated in place.
__global__ __launch_bounds__(256) void k_bn_fused(const float* __restrict__ h,
                                                  const float* __restrict__ gamma,
                                                  const float* __restrict__ beta,
                                                  float* __restrict__ x,
                                                  _Float16* __restrict__ ohi,
                                                  _Float16* __restrict__ olo,
                                                  int res) {
  __shared__ double ls[256], lq[256];
  __shared__ float bc[2];
  int g = blockIdx.x;
  int tid = threadIdx.x;
  float v[16];
  double s = 0.0, q = 0.0;
#pragma unroll
  for (int i = 0; i < 16; ++i) {
    int idx = i * 256 + tid;
    int bb = idx >> 9, c = idx & 511;
    float f = h[((size_t)(bb * 256 + g) << 9) + c];
    v[i] = f;
    double d = (double)f;
    s += d; q += d * d;
  }
  ls[tid] = s; lq[tid] = q;
  __syncthreads();
  for (int off = 128; off; off >>= 1) {
    if (tid < off) { ls[tid] += ls[tid + off]; lq[tid] += lq[tid + off]; }
    __syncthreads();
  }
  if (tid == 0) {
    double mean = ls[0] * (1.0 / 4096.0);
    double var = lq[0] * (1.0 / 4096.0) - mean * mean;
    if (var < 0.0) var = 0.0;
    float rstd = (float)rsqrt(var + 1e-5);
    float a = gamma[g] * rstd;
    bc[0] = a;
    bc[1] = beta[g] - (float)mean * a;
  }
  __syncthreads();
  float a = bc[0], b2 = bc[1];
#pragma unroll
  for (int i = 0; i < 16; ++i) {
    int idx = i * 256 + tid;
    int bb = idx >> 9, c = idx & 511;
    size_t o = ((size_t)(bb * 256 + g) << 9) + c;
    float y = fmaf(v[i], a, b2);
    if (res) y += x[o];
    y = fmaxf(y, 0.f);
    if (res) x[o] = y;
    _Float16 hi, lo; split_hl(y, hi, lo);
    ohi[o] = hi; olo[o] = lo;
  }
}

// ---------------------------------------------------------------------------
// Build xcatT[b][p][c] hi/lo (c<512: unpool scramble of x; c>=512: inp^T).
__global__ __launch_bounds__(256) void k_xcatT(const float* __restrict__ x,
                                               const int* __restrict__ cntI,
                                               const int* __restrict__ gl,
                                               const float* __restrict__ inp,
                                               _Float16* __restrict__ xch,
                                               _Float16* __restrict__ xcl) {
  __shared__ float tl[64][65];
  __shared__ int lab[1024];
  __shared__ float ic[256];
  int t = threadIdx.x;
  int b = blockIdx.y, p0 = blockIdx.x * 64;
  for (int k = t; k < 1024; k += 256) lab[k] = gl[b * 1024 + k];
  if (t < 256) ic[t] = 1.0f / ((float)cntI[b * 256 + t] + 1e-7f);
  __syncthreads();
  for (int pp = 0; pp < 64; ++pp) {
    int p = p0 + pp;
    int p9 = p >> 9, c2 = p & 511;
    const float* xb = x + (size_t)b * 131072 + c2;
    size_t obase = ((size_t)b * 1024 + p) * 1024;
#pragma unroll
    for (int ch = 0; ch < 512; ch += 256) {
      int c = ch + t;
      int g = lab[2 * c + p9];
      float v = xb[(size_t)g * 512] * ic[g];
      _Float16 hi, lo; split_hl(v, hi, lo);
      xch[obase + c] = hi; xcl[obase + c] = lo;
    }
  }
  for (int ct = 0; ct < 512; ct += 64) {
    __syncthreads();
    for (int k = t; k < 4096; k += 256) {
      int i = k >> 6, j = k & 63;
      tl[i][j] = inp[(size_t)b * 524288 + (size_t)(ct + i) * 1024 + p0 + j];
    }
    __syncthreads();
    for (int k = t; k < 4096; k += 256) {
      int i = k >> 6, j = k & 63;
      float v = tl[j][i];
      _Float16 hi, lo; split_hl(v, hi, lo);
      size_t o = ((size_t)b * 1024 + p0 + i) * 1024 + 512 + ct + j;
      xch[o] = hi; xcl[o] = lo;
    }
  }
}

// ---------------------------------------------------------------------------
extern "C" void kernel_launch(void* const* d_in, const int* in_sizes, int n_in,
                              void* d_out, int out_size, void* d_ws, size_t ws_size,
                              hipStream_t stream) {
  const float* inp   = (const float*)d_in[0];
  const int*   gl    = (const int*)d_in[1];
  const float* adj   = (const float*)d_in[2];
  const float* w1    = (const float*)d_in[3];
  const float* wg    = (const float*)d_in[4];
  const float* w2    = (const float*)d_in[5];
  const float* bng   = (const float*)d_in[6];
  const float* bnb   = (const float*)d_in[7];
  const float* convw = (const float*)d_in[8];
  const float* convb = (const float*)d_in[9];
  float* out = (float*)d_out;
  float* ws = (float*)d_ws;

  _Float16* wgchi = (_Float16*)(ws + OFF_WGCH);
  _Float16* wgclo = (_Float16*)(ws + OFF_WGCL);
  _Float16* coefhi = (_Float16*)(ws + OFF_COEFH);
  _Float16* coeflo = (_Float16*)(ws + OFF_COEFL);
  float* x     = ws + OFF_X;
  int*   cntI  = (int*)(ws + OFF_CNTI);
  int*   lists = (int*)(ws + OFF_LISTS);
  int*   csrO  = (int*)(ws + OFF_CSRO);
  unsigned short* csrV = (unsigned short*)(ws + OFF_CSRV);
  _Float16* w1hi = (_Float16*)(ws + OFF_W1H);
  _Float16* w1lo = (_Float16*)(ws + OFF_W1L);
  _Float16* w2hi = (_Float16*)(ws + OFF_W2H);
  _Float16* w2lo = (_Float16*)(ws + OFF_W2L);
  _Float16* cwhi = (_Float16*)(ws + OFF_CWH);
  _Float16* cwlo = (_Float16*)(ws + OFF_CWL);
  _Float16* xhi  = (_Float16*)(ws + OFF_XH);
  _Float16* xlo  = (_Float16*)(ws + OFF_XL);
  _Float16* hhi  = (_Float16*)(ws + OFF_HH);
  _Float16* hlo  = (_Float16*)(ws + OFF_HL);
  float* t2 = ws + OFF_BIG;
  float* e  = ws + OFF_BIG;
  _Float16* eth = (_Float16*)(ws + OFF_BIG + 9437184);
  _Float16* etl = (_Float16*)(ws + OFF_BIG + 14155776);
  _Float16* xch = (_Float16*)(ws + OFF_BIG);
  _Float16* xcl = (_Float16*)(ws + OFF_BIG + 4194304);
  float* ga = ws + OFF_GA;
  float* h1 = ws + OFF_H1;
  float* h2 = ws + OFF_H2;

  hipMemsetAsync(cntI, 0, 2048 * 4, stream);

  k_collapse_wg<<<27648, 256, 0, stream>>>(wg, wgchi, wgclo);
  k_split3<<<8192, 256, 0, stream>>>(w1, w2, convw, w1hi, w1lo, w2hi, w2lo, cwhi, cwlo);
  k_lists<<<32, 256, 0, stream>>>(gl, cntI, lists);
  k_csr<<<1, 256, 0, stream>>>(cntI, lists, csrO, csrV);
  k_t2_gather<<<dim3(128, 9), 256, 0, stream>>>(adj, csrO, csrV, t2);
  k_ga_gather<<<1152, 256, 0, stream>>>(t2, cntI, lists, ga);
  k_coef<<<18432, 256, 0, stream>>>(ga, coefhi, coeflo);
  k_pool_csr<<<512, 256, 0, stream>>>(inp, csrO, csrV, x, xhi, xlo);

  for (int i = 0; i < 3; ++i) {
    // dense1: h1 = x @ w1^T
    k_mfma_nt3f_64<<<dim3(8, 32), 256, 0, stream>>>(xhi, xlo, w1hi + (size_t)i * 262144,
        w1lo + (size_t)i * 262144, h1, 2048, 512, 512);
    k_bn_fused<<<256, 256, 0, stream>>>(h1, bng + (i * 3 + 0) * 256, bnb + (i * 3 + 0) * 256,
        nullptr, hhi, hlo, 0);
    // graph conv: e = h @ wgc^T
    k_mfma_nt3f_128<<<dim3(36, 16), 256, 0, stream>>>(hhi, hlo, wgchi + (size_t)i * 2359296,
        wgclo + (size_t)i * 2359296, e, 2048, 4608, 512);
    // coef einsum via MFMA
    k_eT_split<<<dim3(8, 4, 72), 256, 0, stream>>>(e, eth, etl);
    k_einsum_mfma<<<dim3(8, 4, 8), 256, 0, stream>>>(coefhi, coeflo, eth, etl, h2);
    k_bn_fused<<<256, 256, 0, stream>>>(h2, bng + (i * 3 + 1) * 256, bnb + (i * 3 + 1) * 256,
        nullptr, hhi, hlo, 0);
    // dense2: h1 = h @ w2^T
    k_mfma_nt3f_64<<<dim3(8, 32), 256, 0, stream>>>(hhi, hlo, w2hi + (size_t)i * 262144,
        w2lo + (size_t)i * 262144, h1, 2048, 512, 512);
    k_bn_fused<<<256, 256, 0, stream>>>(h1, bng + (i * 3 + 2) * 256, bnb + (i * 3 + 2) * 256,
        x, xhi, xlo, 1);
  }

  k_xcatT<<<dim3(16, 8), 256, 0, stream>>>(x, cntI, gl, inp, xch, xcl);
  // out[b] = convw @ xcatT[b]^T + bias
  k_mfma_nt3f<<<dim3(16, 4, 8), 256, 0, stream>>>(cwhi, cwlo, xch, xcl, out, convb,
      512, 1024, 1024, 1048576, 524288);
}

// Round 3
// 641.892 us; speedup vs baseline: 1.2042x; 1.0358x over previous
//
#include <hip/hip_runtime.h>
#include <math.h>

// Problem constants: B=8, C=512, H=W=32, N=1024, G=256, R=9
using half8 = __attribute__((ext_vector_type(8))) _Float16;
using f32x4 = __attribute__((ext_vector_type(4))) float;

// Workspace layout (f32 slots)
static constexpr size_t OFF_WGCH  = 0;           // 3*4608*512 halfs
static constexpr size_t OFF_WGCL  = 3538944;
static constexpr size_t OFF_COEF  = 7077888;     // rowsum (18432 f32) lives here now
static constexpr size_t OFF_COEFH = 11796480;    // 4718592 halfs
static constexpr size_t OFF_COEFL = 14155776;
static constexpr size_t OFF_X     = 16515072;    // 1048576 f32
static constexpr size_t OFF_CNT   = 17563648;    // 2048 f32 (unused)
static constexpr size_t OFF_CNTI  = 17565696;    // 2048 int
static constexpr size_t OFF_LISTS = 17567744;    // 98304 int
static constexpr size_t OFF_CSRO  = 17666048;    // 2049 int (pad to 2304)
static constexpr size_t OFF_CSRV  = 17668352;    // 8192 u16
static constexpr size_t OFF_BNA   = 17672448;    // 256 (unused)
static constexpr size_t OFF_BNB   = 17672704;    // 256 (unused)
static constexpr size_t OFF_W1H   = 17672960;    // 3*512*512 halfs
static constexpr size_t OFF_W1L   = 18066176;
static constexpr size_t OFF_W2H   = 18459392;
static constexpr size_t OFF_W2L   = 18852608;
static constexpr size_t OFF_CWH   = 19245824;    // 512*1024 halfs
static constexpr size_t OFF_CWL   = 19507968;
static constexpr size_t OFF_XH    = 19770112;    // 2048*512 halfs
static constexpr size_t OFF_XL    = 20294400;
static constexpr size_t OFF_HH    = 20818688;
static constexpr size_t OFF_HL    = 21342976;
static constexpr size_t OFF_BIG   = 21867264;    // 18874368 f32 region
static constexpr size_t OFF_GA    = 40741632;    // 4718592 f32 (gaT); h1/h2 alias after coef
static constexpr size_t OFF_H1    = OFF_GA;
static constexpr size_t OFF_H2    = OFF_GA + 1048576;

__device__ inline void split_hl(float v, _Float16& hi, _Float16& lo) {
  hi = (_Float16)v;
  lo = (_Float16)(v - (float)hi);
}

// Direct global->LDS DMA, 16 B per lane. LDS dest = wave-uniform base + lane*16.
__device__ inline void gll16(const void* g, void* l) {
  __builtin_amdgcn_global_load_lds(
      (__attribute__((address_space(1))) void*)(size_t)g,
      (__attribute__((address_space(3))) void*)(size_t)l, 16, 0, 0);
}

// ---------------------------------------------------------------------------
// wgc[i][j][c] = sum_r wg[i][j][r*512+c] -> fp16 hi/lo
__global__ __launch_bounds__(256) void k_collapse_wg(const float* __restrict__ wg,
                                                     _Float16* __restrict__ whi,
                                                     _Float16* __restrict__ wlo) {
  size_t idx = (size_t)blockIdx.x * 256 + threadIdx.x;   // 3*4608*512
  size_t i = idx / (4608u * 512u);
  size_t rem = idx % (4608u * 512u);
  size_t j = rem / 512u, c = rem % 512u;
  const float* p = wg + i * 4608ull * 4608ull + j * 4608ull + c;
  float s = 0.f;
#pragma unroll
  for (int r = 0; r < 9; ++r) s += p[r * 512];
  _Float16 hi, lo; split_hl(s, hi, lo);
  whi[idx] = hi; wlo[idx] = lo;
}

// Merged hi/lo split for w1, w2, convw in one dispatch.
__global__ __launch_bounds__(256) void k_split3(const float* __restrict__ w1,
                                                const float* __restrict__ w2,
                                                const float* __restrict__ cw,
                                                _Float16* __restrict__ w1h, _Float16* __restrict__ w1l,
                                                _Float16* __restrict__ w2h, _Float16* __restrict__ w2l,
                                                _Float16* __restrict__ cwh, _Float16* __restrict__ cwl) {
  size_t idx = (size_t)blockIdx.x * 256 + threadIdx.x;   // 2097152 total
  const float* s; _Float16 *H, *L; size_t o;
  if (idx < 786432) { s = w1; H = w1h; L = w1l; o = idx; }
  else if (idx < 1572864) { s = w2; H = w2h; L = w2l; o = idx - 786432; }
  else { s = cw; H = cwh; L = cwl; o = idx - 1572864; }
  _Float16 hi, lo; split_hl(s[o], hi, lo);
  H[o] = hi; L[o] = lo;
}

// ---------------------------------------------------------------------------
__global__ __launch_bounds__(256) void k_lists(const int* __restrict__ gl,
                                               int* __restrict__ cntI,
                                               int* __restrict__ lists) {
  int idx = blockIdx.x * 256 + threadIdx.x;  // 8192
  int b = idx >> 10, n = idx & 1023;
  int h = gl[idx];
  int pos = atomicAdd(&cntI[b * 256 + h], 1);
  if (pos < 48) lists[(b * 256 + h) * 48 + pos] = n;
}

// Build CSR: csr_off[2049] (int), csr_val (u16 n-indices grouped by bg)
__global__ __launch_bounds__(256) void k_csr(const int* __restrict__ cntI,
                                             const int* __restrict__ lists,
                                             int* __restrict__ csr_off,
                                             unsigned short* __restrict__ csr_val) {
  __shared__ int wsum[256];
  __shared__ int tot[257];
  int t = threadIdx.x;
  int base = t * 8;
  int loc[8]; int s = 0;
#pragma unroll
  for (int i = 0; i < 8; ++i) {
    int c = cntI[base + i]; if (c > 48) c = 48;
    loc[i] = s; s += c;
  }
  wsum[t] = s;
  __syncthreads();
  if (t == 0) {
    int a = 0;
    for (int i = 0; i < 256; ++i) { tot[i] = a; a += wsum[i]; }
    tot[256] = a;
  }
  __syncthreads();
  int off0 = tot[t];
#pragma unroll
  for (int i = 0; i < 8; ++i) {
    int bg = base + i;
    int o = off0 + loc[i];
    csr_off[bg] = o;
    int c = cntI[bg]; if (c > 48) c = 48;
    for (int j = 0; j < c; ++j)
      csr_val[o + j] = (unsigned short)(lists[bg * 48 + j] & 1023);
  }
  if (t == 0) csr_off[2048] = tot[256];
}

// ---------------------------------------------------------------------------
// Fused t2+ga: gaT[b,r,h,g] = sum_{m in members(b,g)} sum_{n in members(b,h)} adj[r,n,m]
// Block per (b,h). Phase 1: u[r][m] = sum_{n in h} adj[r,n,m] accumulated in
// registers (thread t owns m in {t, t+256, t+512, t+768}); fully coalesced row
// adds, adj re-reads (8x across b) are L3-resident. Phase 2: LDS gather by g,
// coalesced 1KB-row writes of gaT. The 151 MB t2 HBM round-trip is eliminated.
__global__ __launch_bounds__(256) void k_t2ga(const float* __restrict__ adj,
                                              const int* __restrict__ cntI,
                                              const int* __restrict__ lists,
                                              float* __restrict__ gaT) {
  __shared__ float ul[9][1024];
  __shared__ int lsh[48];
  int t = threadIdx.x;
  int b = blockIdx.x >> 8, h = blockIdx.x & 255;
  int cnt = cntI[b * 256 + h]; if (cnt > 48) cnt = 48;
  if (t < cnt) lsh[t] = lists[(b * 256 + h) * 48 + t];
  __syncthreads();
  float u[9][4];
#pragma unroll
  for (int r = 0; r < 9; ++r)
#pragma unroll
    for (int j = 0; j < 4; ++j) u[r][j] = 0.f;
  for (int i = 0; i < cnt; ++i) {
    const float* base = adj + ((size_t)lsh[i] << 10) + t;
#pragma unroll
    for (int r = 0; r < 9; ++r) {
      const float* p = base + (size_t)r * 1048576;
      u[r][0] += p[0];
      u[r][1] += p[256];
      u[r][2] += p[512];
      u[r][3] += p[768];
    }
  }
#pragma unroll
  for (int r = 0; r < 9; ++r)
#pragma unroll
    for (int j = 0; j < 4; ++j) ul[r][j * 256 + t] = u[r][j];
  __syncthreads();
  int g = t;
  int cg = cntI[b * 256 + g]; if (cg > 48) cg = 48;
  const int* lg = lists + (b * 256 + g) * 48;
  float s[9];
#pragma unroll
  for (int r = 0; r < 9; ++r) s[r] = 0.f;
  for (int i = 0; i < cg; ++i) {
    int m = lg[i];
#pragma unroll
    for (int r = 0; r < 9; ++r) s[r] += ul[r][m];
  }
#pragma unroll
  for (int r = 0; r < 9; ++r)
    gaT[(((size_t)(b * 9 + r)) * 256 + h) * 256 + g] = s[r];
}

// rowsum[z,g] = sum_h gaT[z,h,g] + done per (z = b*9+r) block, coalesced.
__global__ __launch_bounds__(256) void k_gasum(const float* __restrict__ gaT,
                                               float* __restrict__ rowsum) {
  int z = blockIdx.x;            // 72
  int t = threadIdx.x;           // g
  const float* p = gaT + ((size_t)z * 256) * 256 + t;
  float s = 0.f;
  for (int h = 0; h < 256; ++h) s += p[(size_t)h * 256];
  rowsum[z * 256 + t] = s;
}

// coef[b,r,g,h] = num / (rowsum + 1) from gaT via 64x64 LDS transpose tiles;
// writes fp16 hi/lo in the [g][h]-contiguous layout the einsum consumes.
__global__ __launch_bounds__(256) void k_coef_t(const float* __restrict__ gaT,
                                                const float* __restrict__ rowsum,
                                                _Float16* __restrict__ chi,
                                                _Float16* __restrict__ clo) {
  __shared__ float tl[64][65];
  __shared__ float tlf[64][65];
  __shared__ float rs[64];
  int t = threadIdx.x;
  int z = blockIdx.y;            // b*9+r
  int b = z / 9, r = z % 9;
  int tile = blockIdx.x;         // 16
  int h0 = (tile & 3) * 64, g0 = (tile >> 2) * 64;
  size_t base  = ((size_t)z * 256 + h0) * 256 + g0;
  size_t baseF = ((size_t)((7 - b) * 9 + r) * 256 + h0) * 256 + g0;
  for (int k = t; k < 4096; k += 256) {
    int i = k >> 6, j = k & 63;
    tl[i][j]  = gaT[base  + (size_t)i * 256 + j];
    tlf[i][j] = gaT[baseF + (size_t)i * 256 + j];
  }
  if (t < 64) rs[t] = rowsum[z * 256 + g0 + t] + 1.0f;
  __syncthreads();
  for (int k = t; k < 4096; k += 256) {
    int i2 = k >> 6, j2 = k & 63;        // i2: g-local, j2: h-local
    float v = tl[j2][i2], vf = tlf[j2][i2];
    float num = (r == 3) ? v : fmaxf(v - vf, 0.f);
    float c = num / rs[i2];
    _Float16 hi, lo; split_hl(c, hi, lo);
    size_t o = ((size_t)z * 256 + g0 + i2) * 256 + h0 + j2;
    chi[o] = hi; clo[o] = lo;
  }
}

// ---------------------------------------------------------------------------
// Pool via CSR gather; also emits x hi/lo halves (fused split).
__global__ __launch_bounds__(256) void k_pool_csr(const float* __restrict__ inp,
                                                  const int* __restrict__ csr_off,
                                                  const unsigned short* __restrict__ csr_val,
                                                  float* __restrict__ x,
                                                  _Float16* __restrict__ xh,
                                                  _Float16* __restrict__ xl) {
  __shared__ float rows[8][1032];         // 33 KB
  __shared__ int offs[257];
  __shared__ unsigned short vals[1024];
  int t = threadIdx.x;
  int b = blockIdx.x >> 6, cch = blockIdx.x & 63;
  const float4* src = (const float4*)(inp + (size_t)b * 524288 + (size_t)cch * 8 * 1024);
  for (int k = t; k < 2048; k += 256) {
    float4 v = src[k];
    int c = k >> 8;
    int m = (k & 255) << 2;
    *(float4*)&rows[c][m] = v;
  }
  for (int k = t; k < 257; k += 256) offs[k] = csr_off[b * 256 + k];
  __syncthreads();
  int vbase = offs[0];
  int nv = offs[256] - vbase;
  for (int k = t; k < nv; k += 256) vals[k] = csr_val[vbase + k];
  __syncthreads();
  int g = t;
  int o0 = offs[g] - vbase, o1 = offs[g + 1] - vbase;
  float s[8] = {0.f, 0.f, 0.f, 0.f, 0.f, 0.f, 0.f, 0.f};
  for (int i = o0; i < o1; ++i) {
    int n = vals[i];
#pragma unroll
    for (int c = 0; c < 8; ++c) s[c] += rows[c][n];
  }
  const float sc = 1.0f / (1.0f + 1e-7f);
  size_t xbase = ((size_t)b * 256 + g) * 512 + cch * 8;
#pragma unroll
  for (int c = 0; c < 8; ++c) {
    float v = s[c] * sc;
    x[xbase + c] = v;
    _Float16 hi, lo; split_hl(v, hi, lo);
    xh[xbase + c] = hi; xl[xbase + c] = lo;
  }
}

// ---------------------------------------------------------------------------
// Fused hi/lo NT MFMA, 128(M) x 64(N) tile, 4 waves 2x2 (wave: 64x32).
// Double-buffered gll16 staging.
__global__ __launch_bounds__(256) void k_mfma_nt3f(const _Float16* __restrict__ Ahi,
                                                   const _Float16* __restrict__ Alo,
                                                   const _Float16* __restrict__ Bhi,
                                                   const _Float16* __restrict__ Blo,
                                                   float* __restrict__ C,
                                                   const float* __restrict__ bias,
                                                   int M, int N, int K,
                                                   size_t Bbs, size_t Cbs) {
  __shared__ __align__(16) _Float16 Ash[2][128][32];
  __shared__ __align__(16) _Float16 Asl[2][128][32];
  __shared__ __align__(16) _Float16 Bsh[2][64][32];
  __shared__ __align__(16) _Float16 Bsl[2][64][32];
  int tid = threadIdx.x;
  int z = blockIdx.z;
  const _Float16* Bh = Bhi + (size_t)z * Bbs;
  const _Float16* Bl = Blo + (size_t)z * Bbs;
  float* Cz = C + (size_t)z * Cbs;
  int bm = blockIdx.y * 128, bn = blockIdx.x * 64;
  int w = tid >> 6, lane = tid & 63;
  int wr = w >> 1, wc = w & 1;
  int l15 = lane & 15, l4 = lane >> 4;
  int rsub = lane >> 2;
  int qk = (lane & 3) * 8;
  int ar = w * 16 + rsub;
  int ar2 = ar + 64;
  f32x4 acc[4][2];
#pragma unroll
  for (int m = 0; m < 4; ++m)
#pragma unroll
    for (int n = 0; n < 2; ++n) acc[m][n] = (f32x4){0.f, 0.f, 0.f, 0.f};
  auto STG = [&](int bi, int k0) {
    gll16(Ahi + (size_t)(bm + ar) * K + k0 + qk,  &Ash[bi][w * 16][0]);
    gll16(Ahi + (size_t)(bm + ar2) * K + k0 + qk, &Ash[bi][w * 16 + 64][0]);
    gll16(Alo + (size_t)(bm + ar) * K + k0 + qk,  &Asl[bi][w * 16][0]);
    gll16(Alo + (size_t)(bm + ar2) * K + k0 + qk, &Asl[bi][w * 16 + 64][0]);
    gll16(Bh + (size_t)(bn + ar) * K + k0 + qk,   &Bsh[bi][w * 16][0]);
    gll16(Bl + (size_t)(bn + ar) * K + k0 + qk,   &Bsl[bi][w * 16][0]);
  };
  int nt = K >> 5;
  STG(0, 0);
  int cur = 0;
  for (int t = 0; t < nt; ++t, cur ^= 1) {
    __syncthreads();
    if (t + 1 < nt) STG(cur ^ 1, (t + 1) << 5);
    half8 afh[4], afl[4], bfh[2], bfl[2];
#pragma unroll
    for (int m = 0; m < 4; ++m) {
      afh[m] = *(const half8*)&Ash[cur][wr * 64 + m * 16 + l15][l4 * 8];
      afl[m] = *(const half8*)&Asl[cur][wr * 64 + m * 16 + l15][l4 * 8];
    }
#pragma unroll
    for (int n = 0; n < 2; ++n) {
      bfh[n] = *(const half8*)&Bsh[cur][wc * 32 + n * 16 + l15][l4 * 8];
      bfl[n] = *(const half8*)&Bsl[cur][wc * 32 + n * 16 + l15][l4 * 8];
    }
#pragma unroll
    for (int m = 0; m < 4; ++m)
#pragma unroll
      for (int n = 0; n < 2; ++n) {
        acc[m][n] = __builtin_amdgcn_mfma_f32_16x16x32_f16(afh[m], bfh[n], acc[m][n], 0, 0, 0);
        acc[m][n] = __builtin_amdgcn_mfma_f32_16x16x32_f16(afl[m], bfh[n], acc[m][n], 0, 0, 0);
        acc[m][n] = __builtin_amdgcn_mfma_f32_16x16x32_f16(afh[m], bfl[n], acc[m][n], 0, 0, 0);
      }
  }
#pragma unroll
  for (int m = 0; m < 4; ++m)
#pragma unroll
    for (int n = 0; n < 2; ++n)
#pragma unroll
      for (int rr = 0; rr < 4; ++rr) {
        int row = bm + wr * 64 + m * 16 + l4 * 4 + rr;
        int col = bn + wc * 32 + n * 16 + l15;
        float v = acc[m][n][rr];
        if (bias) v += bias[row];
        Cz[(size_t)row * N + col] = v;
      }
}

// ---------------------------------------------------------------------------
// 64x64-tile variant (4 waves 2x2, wave: 32x32), double-buffered.
__global__ __launch_bounds__(256) void k_mfma_nt3f_64(const _Float16* __restrict__ Ahi,
                                                      const _Float16* __restrict__ Alo,
                                                      const _Float16* __restrict__ Bhi,
                                                      const _Float16* __restrict__ Blo,
                                                      float* __restrict__ C,
                                                      int M, int N, int K) {
  __shared__ __align__(16) _Float16 Ash[2][64][32];
  __shared__ __align__(16) _Float16 Asl[2][64][32];
  __shared__ __align__(16) _Float16 Bsh[2][64][32];
  __shared__ __align__(16) _Float16 Bsl[2][64][32];
  int tid = threadIdx.x;
  int bm = blockIdx.y * 64, bn = blockIdx.x * 64;
  int w = tid >> 6, lane = tid & 63;
  int wr = w >> 1, wc = w & 1;
  int l15 = lane & 15, l4 = lane >> 4;
  int rsub = lane >> 2;
  int qk = (lane & 3) * 8;
  int ar = w * 16 + rsub;
  f32x4 acc[2][2];
#pragma unroll
  for (int m = 0; m < 2; ++m)
#pragma unroll
    for (int n = 0; n < 2; ++n) acc[m][n] = (f32x4){0.f, 0.f, 0.f, 0.f};
  auto STG = [&](int bi, int k0) {
    gll16(Ahi + (size_t)(bm + ar) * K + k0 + qk, &Ash[bi][w * 16][0]);
    gll16(Alo + (size_t)(bm + ar) * K + k0 + qk, &Asl[bi][w * 16][0]);
    gll16(Bhi + (size_t)(bn + ar) * K + k0 + qk, &Bsh[bi][w * 16][0]);
    gll16(Blo + (size_t)(bn + ar) * K + k0 + qk, &Bsl[bi][w * 16][0]);
  };
  int nt = K >> 5;
  STG(0, 0);
  int cur = 0;
  for (int t = 0; t < nt; ++t, cur ^= 1) {
    __syncthreads();
    if (t + 1 < nt) STG(cur ^ 1, (t + 1) << 5);
    half8 afh[2], afl[2], bfh[2], bfl[2];
#pragma unroll
    for (int m = 0; m < 2; ++m) {
      afh[m] = *(const half8*)&Ash[cur][wr * 32 + m * 16 + l15][l4 * 8];
      afl[m] = *(const half8*)&Asl[cur][wr * 32 + m * 16 + l15][l4 * 8];
    }
#pragma unroll
    for (int n = 0; n < 2; ++n) {
      bfh[n] = *(const half8*)&Bsh[cur][wc * 32 + n * 16 + l15][l4 * 8];
      bfl[n] = *(const half8*)&Bsl[cur][wc * 32 + n * 16 + l15][l4 * 8];
    }
#pragma unroll
    for (int m = 0; m < 2; ++m)
#pragma unroll
      for (int n = 0; n < 2; ++n) {
        acc[m][n] = __builtin_amdgcn_mfma_f32_16x16x32_f16(afh[m], bfh[n], acc[m][n], 0, 0, 0);
        acc[m][n] = __builtin_amdgcn_mfma_f32_16x16x32_f16(afl[m], bfh[n], acc[m][n], 0, 0, 0);
        acc[m][n] = __builtin_amdgcn_mfma_f32_16x16x32_f16(afh[m], bfl[n], acc[m][n], 0, 0, 0);
      }
  }
#pragma unroll
  for (int m = 0; m < 2; ++m)
#pragma unroll
    for (int n = 0; n < 2; ++n)
#pragma unroll
      for (int rr = 0; rr < 4; ++rr) {
        int row = bm + wr * 32 + m * 16 + l4 * 4 + rr;
        int col = bn + wc * 32 + n * 16 + l15;
        C[(size_t)row * N + col] = acc[m][n][rr];
      }
}

// ---------------------------------------------------------------------------
// 128x128-tile variant (4 waves 2x2, wave: 64x64), double-buffered (64 KB LDS).
__global__ __launch_bounds__(256) void k_mfma_nt3f_128(const _Float16* __restrict__ Ahi,
                                                       const _Float16* __restrict__ Alo,
                                                       const _Float16* __restrict__ Bhi,
                                                       const _Float16* __restrict__ Blo,
                                                       float* __restrict__ C,
                                                       int M, int N, int K) {
  __shared__ __align__(16) _Float16 Ash[2][128][32];
  __shared__ __align__(16) _Float16 Asl[2][128][32];
  __shared__ __align__(16) _Float16 Bsh[2][128][32];
  __shared__ __align__(16) _Float16 Bsl[2][128][32];
  int tid = threadIdx.x;
  int bm = blockIdx.y * 128, bn = blockIdx.x * 128;
  int w = tid >> 6, lane = tid & 63;
  int wr = w >> 1, wc = w & 1;
  int l15 = lane & 15, l4 = lane >> 4;
  int rsub = lane >> 2;
  int qk = (lane & 3) * 8;
  int ar = w * 16 + rsub;
  int ar2 = ar + 64;
  f32x4 acc[4][4];
#pragma unroll
  for (int m = 0; m < 4; ++m)
#pragma unroll
    for (int n = 0; n < 4; ++n) acc[m][n] = (f32x4){0.f, 0.f, 0.f, 0.f};
  auto STG = [&](int bi, int k0) {
    gll16(Ahi + (size_t)(bm + ar) * K + k0 + qk,  &Ash[bi][w * 16][0]);
    gll16(Ahi + (size_t)(bm + ar2) * K + k0 + qk, &Ash[bi][w * 16 + 64][0]);
    gll16(Alo + (size_t)(bm + ar) * K + k0 + qk,  &Asl[bi][w * 16][0]);
    gll16(Alo + (size_t)(bm + ar2) * K + k0 + qk, &Asl[bi][w * 16 + 64][0]);
    gll16(Bhi + (size_t)(bn + ar) * K + k0 + qk,  &Bsh[bi][w * 16][0]);
    gll16(Bhi + (size_t)(bn + ar2) * K + k0 + qk, &Bsh[bi][w * 16 + 64][0]);
    gll16(Blo + (size_t)(bn + ar) * K + k0 + qk,  &Bsl[bi][w * 16][0]);
    gll16(Blo + (size_t)(bn + ar2) * K + k0 + qk, &Bsl[bi][w * 16 + 64][0]);
  };
  int nt = K >> 5;
  STG(0, 0);
  int cur = 0;
  for (int t = 0; t < nt; ++t, cur ^= 1) {
    __syncthreads();
    if (t + 1 < nt) STG(cur ^ 1, (t + 1) << 5);
    half8 afh[4], afl[4], bfh[4], bfl[4];
#pragma unroll
    for (int m = 0; m < 4; ++m) {
      afh[m] = *(const half8*)&Ash[cur][wr * 64 + m * 16 + l15][l4 * 8];
      afl[m] = *(const half8*)&Asl[cur][wr * 64 + m * 16 + l15][l4 * 8];
    }
#pragma unroll
    for (int n = 0; n < 4; ++n) {
      bfh[n] = *(const half8*)&Bsh[cur][wc * 64 + n * 16 + l15][l4 * 8];
      bfl[n] = *(const half8*)&Bsl[cur][wc * 64 + n * 16 + l15][l4 * 8];
    }
#pragma unroll
    for (int m = 0; m < 4; ++m)
#pragma unroll
      for (int n = 0; n < 4; ++n) {
        acc[m][n] = __builtin_amdgcn_mfma_f32_16x16x32_f16(afh[m], bfh[n], acc[m][n], 0, 0, 0);
        acc[m][n] = __builtin_amdgcn_mfma_f32_16x16x32_f16(afl[m], bfh[n], acc[m][n], 0, 0, 0);
        acc[m][n] = __builtin_amdgcn_mfma_f32_16x16x32_f16(afh[m], bfl[n], acc[m][n], 0, 0, 0);
      }
  }
#pragma unroll
  for (int m = 0; m < 4; ++m)
#pragma unroll
    for (int n = 0; n < 4; ++n)
#pragma unroll
      for (int rr = 0; rr < 4; ++rr) {
        int row = bm + wr * 64 + m * 16 + l4 * 4 + rr;
        int col = bn + wc * 64 + n * 16 + l15;
        C[(size_t)row * N + col] = acc[m][n][rr];
      }
}

// ---------------------------------------------------------------------------
// Transpose-split e -> eT hi/lo.
__global__ __launch_bounds__(256) void k_eT_split(const float* __restrict__ e,
                                                  _Float16* __restrict__ eth,
                                                  _Float16* __restrict__ etl) {
  __shared__ float tl[64][65];
  int t = threadIdx.x;
  int z = blockIdx.z;          // b*9+r
  int b = z / 9, r = z % 9;
  int h0 = blockIdx.y * 64, c0 = blockIdx.x * 64;
  const float* ez = e + (size_t)b * 1179648 + (size_t)r * 131072;
  for (int k = t; k < 4096; k += 256) {
    int i = k >> 6, j = k & 63;
    tl[i][j] = ez[(size_t)(h0 + i) * 512 + c0 + j];
  }
  __syncthreads();
  for (int k = t; k < 4096; k += 256) {
    int i = k >> 6, j = k & 63;          // i: c-local, j: h-local
    float v = tl[j][i];
    _Float16 hi, lo; split_hl(v, hi, lo);
    size_t o = ((size_t)z * 512 + c0 + i) * 256 + h0 + j;
    eth[o] = hi; etl[o] = lo;
  }
}

// ---------------------------------------------------------------------------
// h2[b,g,c] = sum_r sum_h coef[b,r,g,h] * eT[b,r,c,h]  (NT MFMA, 64x64 tile),
// double-buffered over the flattened (r, k0) loop (72 steps).
__global__ __launch_bounds__(256) void k_einsum_mfma(const _Float16* __restrict__ Ahi,
                                                     const _Float16* __restrict__ Alo,
                                                     const _Float16* __restrict__ Bhi,
                                                     const _Float16* __restrict__ Blo,
                                                     float* __restrict__ h2) {
  __shared__ __align__(16) _Float16 Ash[2][64][32];
  __shared__ __align__(16) _Float16 Asl[2][64][32];
  __shared__ __align__(16) _Float16 Bsh[2][64][32];
  __shared__ __align__(16) _Float16 Bsl[2][64][32];
  int tid = threadIdx.x;
  int b = blockIdx.z;
  int bm = blockIdx.y * 64, bn = blockIdx.x * 64;
  int w = tid >> 6, lane = tid & 63;
  int wr = w >> 1, wc = w & 1;
  int l15 = lane & 15, l4 = lane >> 4;
  int rsub = lane >> 2;
  int qk = (lane & 3) * 8;
  int ar = w * 16 + rsub;
  f32x4 acc[2][2];
#pragma unroll
  for (int m = 0; m < 2; ++m)
#pragma unroll
    for (int n = 0; n < 2; ++n) acc[m][n] = (f32x4){0.f, 0.f, 0.f, 0.f};
  auto STG = [&](int bi, int kk) {
    int r = kk >> 3, k0 = (kk & 7) << 5;
    const _Float16* Ah = Ahi + ((size_t)b * 9 + r) * 65536 + (size_t)(bm + ar) * 256 + k0 + qk;
    const _Float16* Al = Alo + ((size_t)b * 9 + r) * 65536 + (size_t)(bm + ar) * 256 + k0 + qk;
    const _Float16* Bh = Bhi + ((size_t)b * 9 + r) * 131072 + (size_t)(bn + ar) * 256 + k0 + qk;
    const _Float16* Bl = Blo + ((size_t)b * 9 + r) * 131072 + (size_t)(bn + ar) * 256 + k0 + qk;
    gll16(Ah, &Ash[bi][w * 16][0]);
    gll16(Al, &Asl[bi][w * 16][0]);
    gll16(Bh, &Bsh[bi][w * 16][0]);
    gll16(Bl, &Bsl[bi][w * 16][0]);
  };
  STG(0, 0);
  int cur = 0;
  for (int kk = 0; kk < 72; ++kk, cur ^= 1) {
    __syncthreads();
    if (kk + 1 < 72) STG(cur ^ 1, kk + 1);
    half8 afh[2], afl[2], bfh[2], bfl[2];
#pragma unroll
    for (int m = 0; m < 2; ++m) {
      afh[m] = *(const half8*)&Ash[cur][wr * 32 + m * 16 + l15][l4 * 8];
      afl[m] = *(const half8*)&Asl[cur][wr * 32 + m * 16 + l15][l4 * 8];
    }
#pragma unroll
    for (int n = 0; n < 2; ++n) {
      bfh[n] = *(const half8*)&Bsh[cur][wc * 32 + n * 16 + l15][l4 * 8];
      bfl[n] = *(const half8*)&Bsl[cur][wc * 32 + n * 16 + l15][l4 * 8];
    }
#pragma unroll
    for (int m = 0; m < 2; ++m)
#pragma unroll
      for (int n = 0; n < 2; ++n) {
        acc[m][n] = __builtin_amdgcn_mfma_f32_16x16x32_f16(afh[m], bfh[n], acc[m][n], 0, 0, 0);
        acc[m][n] = __builtin_amdgcn_mfma_f32_16x16x32_f16(afl[m], bfh[n], acc[m][n], 0, 0, 0);
        acc[m][n] = __builtin_amdgcn_mfma_f32_16x16x32_f16(afh[m], bfl[n], acc[m][n], 0, 0, 0);
      }
  }
#pragma unroll
  for (int m = 0; m < 2; ++m)
#pragma unroll
    for (int n = 0; n < 2; ++n)
#pragma unroll
      for (int rr = 0; rr < 4; ++rr) {
        int row = bm + wr * 32 + m * 16 + l4 * 4 + rr;
        int col = bn + wc * 32 + n * 16 + l15;
        h2[(size_t)b * 131072 + (size_t)row * 512 + col] = acc[m][n][rr];
      }
}

// ---------------------------------------------------------------------------
// Fused BatchNorm1d: per-group stats (f64) + apply(+residual) + relu + split.
__global__ __launch_bounds__(256) void k_bn_fused(const float* __restrict__ h,
                                                  const float* __restrict__ gamma,
                                                  const float* __restrict__ beta,
                                                  float* __restrict__ x,
                                                  _Float16* __restrict__ ohi,
                                                  _Float16* __restrict__ olo,
                                                  int res) {
  __shared__ double ls[256], lq[256];
  __shared__ float bc[2];
  int g = blockIdx.x;
  int tid = threadIdx.x;
  float v[16];
  double s = 0.0, q = 0.0;
#pragma unroll
  for (int i = 0; i < 16; ++i) {
    int idx = i * 256 + tid;
    int bb = idx >> 9, c = idx & 511;
    float f = h[((size_t)(bb * 256 + g) << 9) + c];
    v[i] = f;
    double d = (double)f;
    s += d; q += d * d;
  }
  ls[tid] = s; lq[tid] = q;
  __syncthreads();
  for (int off = 128; off; off >>= 1) {
    if (tid < off) { ls[tid] += ls[tid + off]; lq[tid] += lq[tid + off]; }
    __syncthreads();
  }
  if (tid == 0) {
    double mean = ls[0] * (1.0 / 4096.0);
    double var = lq[0] * (1.0 / 4096.0) - mean * mean;
    if (var < 0.0) var = 0.0;
    float rstd = (float)rsqrt(var + 1e-5);
    float a = gamma[g] * rstd;
    bc[0] = a;
    bc[1] = beta[g] - (float)mean * a;
  }
  __syncthreads();
  float a = bc[0], b2 = bc[1];
#pragma unroll
  for (int i = 0; i < 16; ++i) {
    int idx = i * 256 + tid;
    int bb = idx >> 9, c = idx & 511;
    size_t o = ((size_t)(bb * 256 + g) << 9) + c;
    float y = fmaf(v[i], a, b2);
    if (res) y += x[o];
    y = fmaxf(y, 0.f);
    if (res) x[o] = y;
    _Float16 hi, lo; split_hl(y, hi, lo);
    ohi[o] = hi; olo[o] = lo;
  }
}

// ---------------------------------------------------------------------------
// Build xcatT[b][p][c] hi/lo (c<512: unpool scramble of x; c>=512: inp^T).
__global__ __launch_bounds__(256) void k_xcatT(const float* __restrict__ x,
                                               const int* __restrict__ cntI,
                                               const int* __restrict__ gl,
                                               const float* __restrict__ inp,
                                               _Float16* __restrict__ xch,
                                               _Float16* __restrict__ xcl) {
  __shared__ float tl[64][65];
  __shared__ int lab[1024];
  __shared__ float ic[256];
  int t = threadIdx.x;
  int b = blockIdx.y, p0 = blockIdx.x * 64;
  for (int k = t; k < 1024; k += 256) lab[k] = gl[b * 1024 + k];
  if (t < 256) ic[t] = 1.0f / ((float)cntI[b * 256 + t] + 1e-7f);
  __syncthreads();
  for (int pp = 0; pp < 64; ++pp) {
    int p = p0 + pp;
    int p9 = p >> 9, c2 = p & 511;
    const float* xb = x + (size_t)b * 131072 + c2;
    size_t obase = ((size_t)b * 1024 + p) * 1024;
#pragma unroll
    for (int ch = 0; ch < 512; ch += 256) {
      int c = ch + t;
      int g = lab[2 * c + p9];
      float v = xb[(size_t)g * 512] * ic[g];
      _Float16 hi, lo; split_hl(v, hi, lo);
      xch[obase + c] = hi; xcl[obase + c] = lo;
    }
  }
  for (int ct = 0; ct < 512; ct += 64) {
    __syncthreads();
    for (int k = t; k < 4096; k += 256) {
      int i = k >> 6, j = k & 63;
      tl[i][j] = inp[(size_t)b * 524288 + (size_t)(ct + i) * 1024 + p0 + j];
    }
    __syncthreads();
    for (int k = t; k < 4096; k += 256) {
      int i = k >> 6, j = k & 63;
      float v = tl[j][i];
      _Float16 hi, lo; split_hl(v, hi, lo);
      size_t o = ((size_t)b * 1024 + p0 + i) * 1024 + 512 + ct + j;
      xch[o] = hi; xcl[o] = lo;
    }
  }
}

// ---------------------------------------------------------------------------
extern "C" void kernel_launch(void* const* d_in, const int* in_sizes, int n_in,
                              void* d_out, int out_size, void* d_ws, size_t ws_size,
                              hipStream_t stream) {
  const float* inp   = (const float*)d_in[0];
  const int*   gl    = (const int*)d_in[1];
  const float* adj   = (const float*)d_in[2];
  const float* w1    = (const float*)d_in[3];
  const float* wg    = (const float*)d_in[4];
  const float* w2    = (const float*)d_in[5];
  const float* bng   = (const float*)d_in[6];
  const float* bnb   = (const float*)d_in[7];
  const float* convw = (const float*)d_in[8];
  const float* convb = (const float*)d_in[9];
  float* out = (float*)d_out;
  float* ws = (float*)d_ws;

  _Float16* wgchi = (_Float16*)(ws + OFF_WGCH);
  _Float16* wgclo = (_Float16*)(ws + OFF_WGCL);
  _Float16* coefhi = (_Float16*)(ws + OFF_COEFH);
  _Float16* coeflo = (_Float16*)(ws + OFF_COEFL);
  float* rowsum = ws + OFF_COEF;
  float* x     = ws + OFF_X;
  int*   cntI  = (int*)(ws + OFF_CNTI);
  int*   lists = (int*)(ws + OFF_LISTS);
  int*   csrO  = (int*)(ws + OFF_CSRO);
  unsigned short* csrV = (unsigned short*)(ws + OFF_CSRV);
  _Float16* w1hi = (_Float16*)(ws + OFF_W1H);
  _Float16* w1lo = (_Float16*)(ws + OFF_W1L);
  _Float16* w2hi = (_Float16*)(ws + OFF_W2H);
  _Float16* w2lo = (_Float16*)(ws + OFF_W2L);
  _Float16* cwhi = (_Float16*)(ws + OFF_CWH);
  _Float16* cwlo = (_Float16*)(ws + OFF_CWL);
  _Float16* xhi  = (_Float16*)(ws + OFF_XH);
  _Float16* xlo  = (_Float16*)(ws + OFF_XL);
  _Float16* hhi  = (_Float16*)(ws + OFF_HH);
  _Float16* hlo  = (_Float16*)(ws + OFF_HL);
  float* e  = ws + OFF_BIG;
  _Float16* eth = (_Float16*)(ws + OFF_BIG + 9437184);
  _Float16* etl = (_Float16*)(ws + OFF_BIG + 14155776);
  _Float16* xch = (_Float16*)(ws + OFF_BIG);
  _Float16* xcl = (_Float16*)(ws + OFF_BIG + 4194304);
  float* gaT = ws + OFF_GA;
  float* h1 = ws + OFF_H1;
  float* h2 = ws + OFF_H2;

  hipMemsetAsync(cntI, 0, 2048 * 4, stream);

  k_collapse_wg<<<27648, 256, 0, stream>>>(wg, wgchi, wgclo);
  k_split3<<<8192, 256, 0, stream>>>(w1, w2, convw, w1hi, w1lo, w2hi, w2lo, cwhi, cwlo);
  k_lists<<<32, 256, 0, stream>>>(gl, cntI, lists);
  k_csr<<<1, 256, 0, stream>>>(cntI, lists, csrO, csrV);
  k_t2ga<<<2048, 256, 0, stream>>>(adj, cntI, lists, gaT);
  k_gasum<<<72, 256, 0, stream>>>(gaT, rowsum);
  k_coef_t<<<dim3(16, 72), 256, 0, stream>>>(gaT, rowsum, coefhi, coeflo);
  k_pool_csr<<<512, 256, 0, stream>>>(inp, csrO, csrV, x, xhi, xlo);

  for (int i = 0; i < 3; ++i) {
    // dense1: h1 = x @ w1^T
    k_mfma_nt3f_64<<<dim3(8, 32), 256, 0, stream>>>(xhi, xlo, w1hi + (size_t)i * 262144,
        w1lo + (size_t)i * 262144, h1, 2048, 512, 512);
    k_bn_fused<<<256, 256, 0, stream>>>(h1, bng + (i * 3 + 0) * 256, bnb + (i * 3 + 0) * 256,
        nullptr, hhi, hlo, 0);
    // graph conv: e = h @ wgc^T
    k_mfma_nt3f_128<<<dim3(36, 16), 256, 0, stream>>>(hhi, hlo, wgchi + (size_t)i * 2359296,
        wgclo + (size_t)i * 2359296, e, 2048, 4608, 512);
    // coef einsum via MFMA
    k_eT_split<<<dim3(8, 4, 72), 256, 0, stream>>>(e, eth, etl);
    k_einsum_mfma<<<dim3(8, 4, 8), 256, 0, stream>>>(coefhi, coeflo, eth, etl, h2);
    k_bn_fused<<<256, 256, 0, stream>>>(h2, bng + (i * 3 + 1) * 256, bnb + (i * 3 + 1) * 256,
        nullptr, hhi, hlo, 0);
    // dense2: h1 = h @ w2^T
    k_mfma_nt3f_64<<<dim3(8, 32), 256, 0, stream>>>(hhi, hlo, w2hi + (size_t)i * 262144,
        w2lo + (size_t)i * 262144, h1, 2048, 512, 512);
    k_bn_fused<<<256, 256, 0, stream>>>(h1, bng + (i * 3 + 2) * 256, bnb + (i * 3 + 2) * 256,
        x, xhi, xlo, 1);
  }

  k_xcatT<<<dim3(16, 8), 256, 0, stream>>>(x, cntI, gl, inp, xch, xcl);
  // out[b] = convw @ xcatT[b]^T + bias
  k_mfma_nt3f<<<dim3(16, 4, 8), 256, 0, stream>>>(cwhi, cwlo, xch, xcl, out, convb,
      512, 1024, 1024, 1048576, 524288);
}